// Round 1
// baseline (2824.713 us; speedup 1.0000x reference)
//
#include <hip/hip_runtime.h>
#include <hip/hip_bf16.h>

// Problem constants
#define NLAYERS 2
#define DMODEL 1024
#define DINNER 2048
#define DSTATE 16
#define DCONV 4
#define DTRANK 64
#define BATCH 2
#define SEQ 1024
#define TOK (BATCH * SEQ)   // 2048 tokens

__device__ __forceinline__ float softplusf(float x) {
    return (x > 20.f) ? x : log1pf(__expf(x));
}
__device__ __forceinline__ float siluf(float x) {
    return x / (1.f + __expf(-x));
}

// ---------------------------------------------------------------------------
// Tiled fp32 GEMM:  C[M][N] = A[M][K] @ W[N][K]^T   (+ epilogue)
// EPI 0: plain store
// EPI 1: softplus(acc + bias[n])      (dt_proj -> delta)
// EPI 2: acc + res[m][n]              (final residual add)
// BM=BN=128, BK=16, 256 threads, 8x8 per thread.
// Assumes M % 128 == 0 and K % 16 == 0 (true for all our shapes);
// N is guarded (needed for N=96).
// ---------------------------------------------------------------------------
template <int EPI>
__global__ __launch_bounds__(256)
void gemm128(const float* __restrict__ A, int lda,
             const float* __restrict__ W, int ldw,
             float* __restrict__ C, int ldc,
             int M, int N, int K,
             const float* __restrict__ bias,
             const float* __restrict__ res, int ldr) {
    constexpr int BM = 128, BN = 128, BK = 16;
    __shared__ float As[BK][BM];
    __shared__ float Bs[BK][BN];

    const int tid = threadIdx.x;
    const int tx = tid & 15;   // col group (8 cols)
    const int ty = tid >> 4;   // row group (8 rows)
    const int m0 = blockIdx.y * BM;
    const int n0 = blockIdx.x * BN;

    const int r0 = tid >> 2;   // 0..63
    const int kv = tid & 3;    // float4 index along k

    float acc[8][8];
#pragma unroll
    for (int i = 0; i < 8; ++i)
#pragma unroll
        for (int j = 0; j < 8; ++j) acc[i][j] = 0.f;

    for (int kt = 0; kt < K; kt += BK) {
#pragma unroll
        for (int rep = 0; rep < 2; ++rep) {
            const int r = r0 + rep * 64;
            // A tile (no m-guard: M%128==0)
            const float4 a4 = *reinterpret_cast<const float4*>(
                &A[(size_t)(m0 + r) * lda + kt + kv * 4]);
            As[kv * 4 + 0][r] = a4.x;
            As[kv * 4 + 1][r] = a4.y;
            As[kv * 4 + 2][r] = a4.z;
            As[kv * 4 + 3][r] = a4.w;
            // W tile (guard n)
            float4 b4 = make_float4(0.f, 0.f, 0.f, 0.f);
            const int n = n0 + r;
            if (n < N)
                b4 = *reinterpret_cast<const float4*>(
                    &W[(size_t)n * ldw + kt + kv * 4]);
            Bs[kv * 4 + 0][r] = b4.x;
            Bs[kv * 4 + 1][r] = b4.y;
            Bs[kv * 4 + 2][r] = b4.z;
            Bs[kv * 4 + 3][r] = b4.w;
        }
        __syncthreads();
#pragma unroll
        for (int kk = 0; kk < BK; ++kk) {
            const float4 a0 = *reinterpret_cast<const float4*>(&As[kk][ty * 8 + 0]);
            const float4 a1 = *reinterpret_cast<const float4*>(&As[kk][ty * 8 + 4]);
            const float4 b0 = *reinterpret_cast<const float4*>(&Bs[kk][tx * 8 + 0]);
            const float4 b1 = *reinterpret_cast<const float4*>(&Bs[kk][tx * 8 + 4]);
            const float av[8] = {a0.x, a0.y, a0.z, a0.w, a1.x, a1.y, a1.z, a1.w};
            const float bv[8] = {b0.x, b0.y, b0.z, b0.w, b1.x, b1.y, b1.z, b1.w};
#pragma unroll
            for (int i = 0; i < 8; ++i)
#pragma unroll
                for (int j = 0; j < 8; ++j)
                    acc[i][j] = fmaf(av[i], bv[j], acc[i][j]);
        }
        __syncthreads();
    }

#pragma unroll
    for (int i = 0; i < 8; ++i) {
        const int m = m0 + ty * 8 + i;
#pragma unroll
        for (int jv = 0; jv < 2; ++jv) {
            const int n = n0 + tx * 8 + jv * 4;
            if (n < N) {  // N%4==0 so whole float4 in range
                float4 v;
                v.x = acc[i][jv * 4 + 0];
                v.y = acc[i][jv * 4 + 1];
                v.z = acc[i][jv * 4 + 2];
                v.w = acc[i][jv * 4 + 3];
                if (EPI == 1) {
                    v.x = softplusf(v.x + bias[n + 0]);
                    v.y = softplusf(v.y + bias[n + 1]);
                    v.z = softplusf(v.z + bias[n + 2]);
                    v.w = softplusf(v.w + bias[n + 3]);
                } else if (EPI == 2) {
                    const float4 rr = *reinterpret_cast<const float4*>(
                        &res[(size_t)m * ldr + n]);
                    v.x += rr.x; v.y += rr.y; v.z += rr.z; v.w += rr.w;
                }
                *reinterpret_cast<float4*>(&C[(size_t)m * ldc + n]) = v;
            }
        }
    }
}

// ---------------------------------------------------------------------------
// Causal depthwise conv1d (+bias) + SiLU.
// xz: [TOK][2*DINNER], use columns [0, DINNER) as xc. u: [TOK][DINNER].
// ---------------------------------------------------------------------------
__global__ __launch_bounds__(256)
void conv_silu(const float* __restrict__ xz,
               const float* __restrict__ cw,   // [DINNER][DCONV]
               const float* __restrict__ cb,   // [DINNER]
               float* __restrict__ u) {
    const int idx = blockIdx.x * 256 + threadIdx.x;  // over TOK*DINNER
    const int d = idx & (DINNER - 1);
    const int token = idx >> 11;  // /2048
    const int l = token & (SEQ - 1);
    float acc = cb[d];
#pragma unroll
    for (int k = 0; k < DCONV; ++k) {
        const int li = l - (DCONV - 1) + k;
        if (li >= 0)
            acc = fmaf(cw[d * DCONV + k],
                       xz[(size_t)(token - (DCONV - 1) + k) * (2 * DINNER) + d],
                       acc);
    }
    u[idx] = siluf(acc);
}

// ---------------------------------------------------------------------------
// Selective scan, fused with D-skip and SiLU(z) gating.
// One 16-lane group per channel d; lane n = state index.
// ---------------------------------------------------------------------------
__global__ __launch_bounds__(256)
void scan_kernel(const float* __restrict__ delta,  // [TOK][DINNER]
                 const float* __restrict__ u,      // [TOK][DINNER]
                 const float* __restrict__ xdbl,   // [TOK][96]: dt|B|C
                 const float* __restrict__ xz,     // [TOK][2*DINNER] (z at 2048+d)
                 const float* __restrict__ A_log,  // [DINNER][DSTATE]
                 const float* __restrict__ Dp,     // [DINNER]
                 float* __restrict__ yout) {       // [TOK][DINNER]
    const int b = blockIdx.y;
    const int d = blockIdx.x * 16 + (threadIdx.x >> 4);
    const int n = threadIdx.x & 15;

    const float A_dn = -__expf(A_log[d * DSTATE + n]);
    const float Dd = Dp[d];
    float h = 0.f;
    const int tok0 = b * SEQ;

    // software pipeline: preload l=0
    int t = tok0;
    float dlt = delta[(size_t)t * DINNER + d];
    float uv = u[(size_t)t * DINNER + d];
    float Bv = xdbl[(size_t)t * 96 + DTRANK + n];
    float Cv = xdbl[(size_t)t * 96 + DTRANK + DSTATE + n];

    for (int l = 0; l < SEQ; ++l) {
        const float dlt_c = dlt, uv_c = uv, Bv_c = Bv, Cv_c = Cv;
        const int tc = tok0 + l;
        if (l + 1 < SEQ) {
            const int tn = tc + 1;
            dlt = delta[(size_t)tn * DINNER + d];
            uv = u[(size_t)tn * DINNER + d];
            Bv = xdbl[(size_t)tn * 96 + DTRANK + n];
            Cv = xdbl[(size_t)tn * 96 + DTRANK + DSTATE + n];
        }
        const float dA = __expf(dlt_c * A_dn);
        h = fmaf(dA, h, dlt_c * Bv_c * uv_c);
        float p = h * Cv_c;
        p += __shfl_xor(p, 1, 16);
        p += __shfl_xor(p, 2, 16);
        p += __shfl_xor(p, 4, 16);
        p += __shfl_xor(p, 8, 16);
        if (n == 0) {
            const float zv = xz[(size_t)tc * (2 * DINNER) + DINNER + d];
            const float y = p + uv_c * Dd;
            yout[(size_t)tc * DINNER + d] = y * siluf(zv);
        }
    }
}

// ---------------------------------------------------------------------------
extern "C" void kernel_launch(void* const* d_in, const int* in_sizes, int n_in,
                              void* d_out, int out_size, void* d_ws, size_t ws_size,
                              hipStream_t stream) {
    const float* x          = (const float*)d_in[0];  // [TOK][DMODEL]
    const float* in_proj_w  = (const float*)d_in[1];  // [L][2*DINNER][DMODEL]
    const float* conv_w     = (const float*)d_in[2];  // [L][DINNER][1][DCONV]
    const float* conv_b     = (const float*)d_in[3];  // [L][DINNER]
    const float* x_proj_w   = (const float*)d_in[4];  // [L][96][DINNER]
    const float* dt_proj_w  = (const float*)d_in[5];  // [L][DINNER][DTRANK]
    const float* dt_proj_b  = (const float*)d_in[6];  // [L][DINNER]
    const float* A_log      = (const float*)d_in[7];  // [L][DINNER][DSTATE]
    const float* Dp         = (const float*)d_in[8];  // [L][DINNER]
    const float* out_proj_w = (const float*)d_in[9];  // [L][DMODEL][DINNER]
    float* out = (float*)d_out;                       // [TOK][DMODEL]

    // workspace layout (floats)
    float* ws = (float*)d_ws;
    float* xz    = ws;                         // TOK*4096
    float* u     = xz    + (size_t)TOK * 4096; // TOK*2048
    float* xdbl  = u     + (size_t)TOK * 2048; // TOK*96
    float* delta = xdbl  + (size_t)TOK * 96;   // TOK*2048
    float* yfull = delta + (size_t)TOK * 2048; // TOK*2048
    float* xbuf  = yfull + (size_t)TOK * 2048; // TOK*1024

    const float* cur_in = x;
    for (int layer = 0; layer < NLAYERS; ++layer) {
        const float* Wi = in_proj_w  + (size_t)layer * (2 * DINNER) * DMODEL;
        const float* cw = conv_w     + (size_t)layer * DINNER * DCONV;
        const float* cb = conv_b     + (size_t)layer * DINNER;
        const float* Wx = x_proj_w   + (size_t)layer * 96 * DINNER;
        const float* Wd = dt_proj_w  + (size_t)layer * DINNER * DTRANK;
        const float* bd = dt_proj_b  + (size_t)layer * DINNER;
        const float* Al = A_log      + (size_t)layer * DINNER * DSTATE;
        const float* Dl = Dp         + (size_t)layer * DINNER;
        const float* Wo = out_proj_w + (size_t)layer * DMODEL * DINNER;

        // 1. xz = cur_in @ W_in^T   (TOK x 4096, K=1024)
        {
            dim3 grid(4096 / 128, TOK / 128);
            gemm128<0><<<grid, 256, 0, stream>>>(cur_in, DMODEL, Wi, DMODEL,
                                                 xz, 2 * DINNER, TOK, 2 * DINNER,
                                                 DMODEL, nullptr, nullptr, 0);
        }
        // 2. u = silu(causal depthwise conv(xc) + b)
        conv_silu<<<(TOK * DINNER) / 256, 256, 0, stream>>>(xz, cw, cb, u);
        // 3. x_dbl = u @ W_x^T   (TOK x 96, K=2048)
        {
            dim3 grid(1, TOK / 128);
            gemm128<0><<<grid, 256, 0, stream>>>(u, DINNER, Wx, DINNER,
                                                 xdbl, 96, TOK, 96, DINNER,
                                                 nullptr, nullptr, 0);
        }
        // 4. delta = softplus(dt @ W_dt^T + b_dt)  (TOK x 2048, K=64)
        {
            dim3 grid(DINNER / 128, TOK / 128);
            gemm128<1><<<grid, 256, 0, stream>>>(xdbl, 96, Wd, DTRANK,
                                                 delta, DINNER, TOK, DINNER,
                                                 DTRANK, bd, nullptr, 0);
        }
        // 5. selective scan + D-skip + silu(z) gate -> yfull
        {
            dim3 grid(DINNER / 16, BATCH);
            scan_kernel<<<grid, 256, 0, stream>>>(delta, u, xdbl, xz, Al, Dl, yfull);
        }
        // 6. out = yfull @ W_out^T (+ residual on last layer)
        {
            dim3 grid(DMODEL / 128, TOK / 128);
            if (layer == NLAYERS - 1) {
                gemm128<2><<<grid, 256, 0, stream>>>(yfull, DINNER, Wo, DINNER,
                                                     out, DMODEL, TOK, DMODEL,
                                                     DINNER, nullptr, x, DMODEL);
            } else {
                gemm128<0><<<grid, 256, 0, stream>>>(yfull, DINNER, Wo, DINNER,
                                                     xbuf, DMODEL, TOK, DMODEL,
                                                     DINNER, nullptr, nullptr, 0);
            }
        }
        cur_in = xbuf;
    }
}

// Round 2
// 1490.638 us; speedup vs baseline: 1.8950x; 1.8950x over previous
//
#include <hip/hip_runtime.h>
#include <hip/hip_bf16.h>

// Problem constants
#define NLAYERS 2
#define DMODEL 1024
#define DINNER 2048
#define DSTATE 16
#define DCONV 4
#define DTRANK 64
#define BATCH 2
#define SEQ 1024
#define TOK (BATCH * SEQ)   // 2048 tokens

#define NCHUNK 16
#define CLEN (SEQ / NCHUNK)  // 64
#define KSPLIT 8             // x_proj K-split

__device__ __forceinline__ float softplusf(float x) {
    return (x > 20.f) ? x : log1pf(__expf(x));
}
__device__ __forceinline__ float siluf(float x) {
    return x / (1.f + __expf(-x));
}

// ---------------------------------------------------------------------------
// Tiled fp32 GEMM:  C[M][N] = A[M][K] @ W[N][K]^T   (+ epilogue)
// EPI 0: plain store; EPI 1: softplus(acc+bias[n]); EPI 2: acc+res[m][n].
// Optional K-split: blockIdx.z selects K-slice [z*kLen, (z+1)*kLen), output
// goes to C + z*cSlice.
// ---------------------------------------------------------------------------
template <int EPI>
__global__ __launch_bounds__(256)
void gemm128(const float* __restrict__ A, int lda,
             const float* __restrict__ W, int ldw,
             float* __restrict__ C, int ldc,
             int M, int N, int kLen, size_t cSlice,
             const float* __restrict__ bias,
             const float* __restrict__ res, int ldr) {
    constexpr int BM = 128, BN = 128, BK = 16;
    __shared__ float As[BK][BM];
    __shared__ float Bs[BK][BN];

    const int tid = threadIdx.x;
    const int tx = tid & 15;
    const int ty = tid >> 4;
    const int m0 = blockIdx.y * BM;
    const int n0 = blockIdx.x * BN;
    const int kbeg = blockIdx.z * kLen;
    const int kend = kbeg + kLen;
    C += (size_t)blockIdx.z * cSlice;

    const int r0 = tid >> 2;
    const int kv = tid & 3;

    float acc[8][8];
#pragma unroll
    for (int i = 0; i < 8; ++i)
#pragma unroll
        for (int j = 0; j < 8; ++j) acc[i][j] = 0.f;

    for (int kt = kbeg; kt < kend; kt += BK) {
#pragma unroll
        for (int rep = 0; rep < 2; ++rep) {
            const int r = r0 + rep * 64;
            const float4 a4 = *reinterpret_cast<const float4*>(
                &A[(size_t)(m0 + r) * lda + kt + kv * 4]);
            As[kv * 4 + 0][r] = a4.x;
            As[kv * 4 + 1][r] = a4.y;
            As[kv * 4 + 2][r] = a4.z;
            As[kv * 4 + 3][r] = a4.w;
            float4 b4 = make_float4(0.f, 0.f, 0.f, 0.f);
            const int n = n0 + r;
            if (n < N)
                b4 = *reinterpret_cast<const float4*>(
                    &W[(size_t)n * ldw + kt + kv * 4]);
            Bs[kv * 4 + 0][r] = b4.x;
            Bs[kv * 4 + 1][r] = b4.y;
            Bs[kv * 4 + 2][r] = b4.z;
            Bs[kv * 4 + 3][r] = b4.w;
        }
        __syncthreads();
#pragma unroll
        for (int kk = 0; kk < BK; ++kk) {
            const float4 a0 = *reinterpret_cast<const float4*>(&As[kk][ty * 8 + 0]);
            const float4 a1 = *reinterpret_cast<const float4*>(&As[kk][ty * 8 + 4]);
            const float4 b0 = *reinterpret_cast<const float4*>(&Bs[kk][tx * 8 + 0]);
            const float4 b1 = *reinterpret_cast<const float4*>(&Bs[kk][tx * 8 + 4]);
            const float av[8] = {a0.x, a0.y, a0.z, a0.w, a1.x, a1.y, a1.z, a1.w};
            const float bv[8] = {b0.x, b0.y, b0.z, b0.w, b1.x, b1.y, b1.z, b1.w};
#pragma unroll
            for (int i = 0; i < 8; ++i)
#pragma unroll
                for (int j = 0; j < 8; ++j)
                    acc[i][j] = fmaf(av[i], bv[j], acc[i][j]);
        }
        __syncthreads();
    }

#pragma unroll
    for (int i = 0; i < 8; ++i) {
        const int m = m0 + ty * 8 + i;
#pragma unroll
        for (int jv = 0; jv < 2; ++jv) {
            const int n = n0 + tx * 8 + jv * 4;
            if (n < N) {
                float4 v;
                v.x = acc[i][jv * 4 + 0];
                v.y = acc[i][jv * 4 + 1];
                v.z = acc[i][jv * 4 + 2];
                v.w = acc[i][jv * 4 + 3];
                if (EPI == 1) {
                    v.x = softplusf(v.x + bias[n + 0]);
                    v.y = softplusf(v.y + bias[n + 1]);
                    v.z = softplusf(v.z + bias[n + 2]);
                    v.w = softplusf(v.w + bias[n + 3]);
                } else if (EPI == 2) {
                    const float4 rr = *reinterpret_cast<const float4*>(
                        &res[(size_t)m * ldr + n]);
                    v.x += rr.x; v.y += rr.y; v.z += rr.z; v.w += rr.w;
                }
                *reinterpret_cast<float4*>(&C[(size_t)m * ldc + n]) = v;
            }
        }
    }
}

// Sum KSPLIT partial GEMM outputs.
__global__ __launch_bounds__(256)
void reduce_ksplit(const float* __restrict__ part, float* __restrict__ out,
                   int n, size_t stride) {
    const int i = blockIdx.x * 256 + threadIdx.x;
    if (i < n) {
        float s = 0.f;
#pragma unroll
        for (int k = 0; k < KSPLIT; ++k) s += part[(size_t)k * stride + i];
        out[i] = s;
    }
}

// ---------------------------------------------------------------------------
// Causal depthwise conv1d (+bias) + SiLU.
// ---------------------------------------------------------------------------
__global__ __launch_bounds__(256)
void conv_silu(const float* __restrict__ xz,
               const float* __restrict__ cw,
               const float* __restrict__ cb,
               float* __restrict__ u) {
    const int idx = blockIdx.x * 256 + threadIdx.x;
    const int d = idx & (DINNER - 1);
    const int token = idx >> 11;
    const int l = token & (SEQ - 1);
    float acc = cb[d];
#pragma unroll
    for (int k = 0; k < DCONV; ++k) {
        const int li = l - (DCONV - 1) + k;
        if (li >= 0)
            acc = fmaf(cw[d * DCONV + k],
                       xz[(size_t)(token - (DCONV - 1) + k) * (2 * DINNER) + d],
                       acc);
    }
    u[idx] = siluf(acc);
}

// ---------------------------------------------------------------------------
// Chunk-parallel selective scan.
// Pass A: per-chunk local scan from h=0; store (h_local, prod dA).
// Pass B: combine across chunks (in-place: hbuf becomes h_init per chunk).
// Pass C: re-run each chunk from h_init; emit y with D-skip + silu(z) gate.
// Layout of hbuf/Pbuf: [b][chunk][d][n]
// ---------------------------------------------------------------------------
__global__ __launch_bounds__(256)
void scan_partial(const float* __restrict__ delta,
                  const float* __restrict__ u,
                  const float* __restrict__ xdbl,
                  const float* __restrict__ A_log,
                  float* __restrict__ hbuf,
                  float* __restrict__ Pbuf) {
    const int b = blockIdx.y / NCHUNK;
    const int c = blockIdx.y % NCHUNK;
    const int d = blockIdx.x * 16 + (threadIdx.x >> 4);
    const int n = threadIdx.x & 15;

    const float A_dn = -__expf(A_log[d * DSTATE + n]);
    float h = 0.f, P = 1.f;
    const int t0 = b * SEQ + c * CLEN;
#pragma unroll 4
    for (int l = 0; l < CLEN; ++l) {
        const int t = t0 + l;
        const float dlt = delta[(size_t)t * DINNER + d];
        const float uv = u[(size_t)t * DINNER + d];
        const float Bv = xdbl[(size_t)t * 96 + DTRANK + n];
        const float dA = __expf(dlt * A_dn);
        h = fmaf(dA, h, dlt * Bv * uv);
        P *= dA;
    }
    const size_t idx = ((size_t)(b * NCHUNK + c) * DINNER + d) * DSTATE + n;
    hbuf[idx] = h;
    Pbuf[idx] = P;
}

__global__ __launch_bounds__(256)
void scan_combine(float* __restrict__ hbuf, const float* __restrict__ Pbuf) {
    const int gid = blockIdx.x * 256 + threadIdx.x;  // over BATCH*DINNER*DSTATE
    const int b = gid / (DINNER * DSTATE);
    const int dn = gid - b * (DINNER * DSTATE);
    const size_t base = (size_t)b * NCHUNK * DINNER * DSTATE + dn;
    float hi = 0.f;
#pragma unroll
    for (int c = 0; c < NCHUNK; ++c) {
        const size_t idx = base + (size_t)c * (DINNER * DSTATE);
        const float hl = hbuf[idx];
        const float Pc = Pbuf[idx];
        hbuf[idx] = hi;            // h_init for chunk c
        hi = fmaf(Pc, hi, hl);
    }
}

__global__ __launch_bounds__(256)
void scan_final(const float* __restrict__ delta,
                const float* __restrict__ u,
                const float* __restrict__ xdbl,
                const float* __restrict__ xz,
                const float* __restrict__ A_log,
                const float* __restrict__ Dp,
                const float* __restrict__ hbuf,
                float* __restrict__ yout) {
    const int b = blockIdx.y / NCHUNK;
    const int c = blockIdx.y % NCHUNK;
    const int d = blockIdx.x * 16 + (threadIdx.x >> 4);
    const int n = threadIdx.x & 15;

    const float A_dn = -__expf(A_log[d * DSTATE + n]);
    const float Dd = Dp[d];
    float h = hbuf[((size_t)(b * NCHUNK + c) * DINNER + d) * DSTATE + n];
    const int t0 = b * SEQ + c * CLEN;
#pragma unroll 2
    for (int l = 0; l < CLEN; ++l) {
        const int t = t0 + l;
        const float dlt = delta[(size_t)t * DINNER + d];
        const float uv = u[(size_t)t * DINNER + d];
        const float Bv = xdbl[(size_t)t * 96 + DTRANK + n];
        const float Cv = xdbl[(size_t)t * 96 + DTRANK + DSTATE + n];
        const float dA = __expf(dlt * A_dn);
        h = fmaf(dA, h, dlt * Bv * uv);
        float p = h * Cv;
        p += __shfl_xor(p, 1, 16);
        p += __shfl_xor(p, 2, 16);
        p += __shfl_xor(p, 4, 16);
        p += __shfl_xor(p, 8, 16);
        if (n == 0) {
            const float zv = xz[(size_t)t * (2 * DINNER) + DINNER + d];
            const float y = p + uv * Dd;
            yout[(size_t)t * DINNER + d] = y * siluf(zv);
        }
    }
}

// ---------------------------------------------------------------------------
extern "C" void kernel_launch(void* const* d_in, const int* in_sizes, int n_in,
                              void* d_out, int out_size, void* d_ws, size_t ws_size,
                              hipStream_t stream) {
    const float* x          = (const float*)d_in[0];
    const float* in_proj_w  = (const float*)d_in[1];
    const float* conv_w     = (const float*)d_in[2];
    const float* conv_b     = (const float*)d_in[3];
    const float* x_proj_w   = (const float*)d_in[4];
    const float* dt_proj_w  = (const float*)d_in[5];
    const float* dt_proj_b  = (const float*)d_in[6];
    const float* A_log      = (const float*)d_in[7];
    const float* Dp         = (const float*)d_in[8];
    const float* out_proj_w = (const float*)d_in[9];
    float* out = (float*)d_out;

    // workspace layout (floats)
    float* ws = (float*)d_ws;
    float* xz    = ws;                          // TOK*4096
    float* u     = xz    + (size_t)TOK * 4096;  // TOK*2048
    float* xdbl  = u     + (size_t)TOK * 2048;  // TOK*96
    float* delta = xdbl  + (size_t)TOK * 96;    // TOK*2048
    float* yfull = delta + (size_t)TOK * 2048;  // TOK*2048
    float* xbuf  = yfull + (size_t)TOK * 2048;  // TOK*1024
    float* xpart = xbuf  + (size_t)TOK * 1024;  // KSPLIT*TOK*96
    float* hbuf  = xpart + (size_t)KSPLIT * TOK * 96;       // B*NC*DI*DS
    float* Pbuf  = hbuf  + (size_t)BATCH * NCHUNK * DINNER * DSTATE;

    const float* cur_in = x;
    for (int layer = 0; layer < NLAYERS; ++layer) {
        const float* Wi = in_proj_w  + (size_t)layer * (2 * DINNER) * DMODEL;
        const float* cw = conv_w     + (size_t)layer * DINNER * DCONV;
        const float* cb = conv_b     + (size_t)layer * DINNER;
        const float* Wx = x_proj_w   + (size_t)layer * 96 * DINNER;
        const float* Wd = dt_proj_w  + (size_t)layer * DINNER * DTRANK;
        const float* bd = dt_proj_b  + (size_t)layer * DINNER;
        const float* Al = A_log      + (size_t)layer * DINNER * DSTATE;
        const float* Dl = Dp         + (size_t)layer * DINNER;
        const float* Wo = out_proj_w + (size_t)layer * DMODEL * DINNER;

        // 1. xz = cur_in @ W_in^T   (TOK x 4096, K=1024)
        {
            dim3 grid(4096 / 128, TOK / 128, 1);
            gemm128<0><<<grid, 256, 0, stream>>>(cur_in, DMODEL, Wi, DMODEL,
                                                 xz, 2 * DINNER, TOK, 2 * DINNER,
                                                 DMODEL, 0, nullptr, nullptr, 0);
        }
        // 2. u = silu(causal depthwise conv(xc) + b)
        conv_silu<<<(TOK * DINNER) / 256, 256, 0, stream>>>(xz, cw, cb, u);
        // 3. x_dbl = u @ W_x^T (TOK x 96, K=2048), split-K over grid.z
        {
            dim3 grid(1, TOK / 128, KSPLIT);
            gemm128<0><<<grid, 256, 0, stream>>>(u, DINNER, Wx, DINNER,
                                                 xpart, 96, TOK, 96,
                                                 DINNER / KSPLIT, (size_t)TOK * 96,
                                                 nullptr, nullptr, 0);
            reduce_ksplit<<<(TOK * 96 + 255) / 256, 256, 0, stream>>>(
                xpart, xdbl, TOK * 96, (size_t)TOK * 96);
        }
        // 4. delta = softplus(dt @ W_dt^T + b_dt)  (TOK x 2048, K=64)
        {
            dim3 grid(DINNER / 128, TOK / 128, 1);
            gemm128<1><<<grid, 256, 0, stream>>>(xdbl, 96, Wd, DTRANK,
                                                 delta, DINNER, TOK, DINNER,
                                                 DTRANK, 0, bd, nullptr, 0);
        }
        // 5. chunk-parallel scan
        {
            dim3 gridA(DINNER / 16, BATCH * NCHUNK);
            scan_partial<<<gridA, 256, 0, stream>>>(delta, u, xdbl, Al, hbuf, Pbuf);
            scan_combine<<<(BATCH * DINNER * DSTATE) / 256, 256, 0, stream>>>(hbuf, Pbuf);
            scan_final<<<gridA, 256, 0, stream>>>(delta, u, xdbl, xz, Al, Dl, hbuf, yfull);
        }
        // 6. out = yfull @ W_out^T (+ residual on last layer)
        {
            dim3 grid(DMODEL / 128, TOK / 128, 1);
            if (layer == NLAYERS - 1) {
                gemm128<2><<<grid, 256, 0, stream>>>(yfull, DINNER, Wo, DINNER,
                                                     out, DMODEL, TOK, DMODEL,
                                                     DINNER, 0, nullptr, x, DMODEL);
            } else {
                gemm128<0><<<grid, 256, 0, stream>>>(yfull, DINNER, Wo, DINNER,
                                                     xbuf, DMODEL, TOK, DMODEL,
                                                     DINNER, 0, nullptr, nullptr, 0);
            }
        }
        cur_in = xbuf;
    }
}

// Round 3
// 657.265 us; speedup vs baseline: 4.2977x; 2.2679x over previous
//
#include <hip/hip_runtime.h>
#include <hip/hip_bf16.h>

// Problem constants
#define NLAYERS 2
#define DMODEL 1024
#define DINNER 2048
#define DSTATE 16
#define DCONV 4
#define DTRANK 64
#define BATCH 2
#define SEQ 1024
#define TOK (BATCH * SEQ)   // 2048 tokens

#define NCHUNK 16
#define CLEN (SEQ / NCHUNK)  // 64
#define KSPLIT 8             // x_proj K-split

typedef short bf16x8 __attribute__((ext_vector_type(8)));
typedef float f32x4 __attribute__((ext_vector_type(4)));

__device__ __forceinline__ float softplusf(float x) {
    return (x > 20.f) ? x : log1pf(__expf(x));
}
__device__ __forceinline__ float siluf(float x) {
    return x / (1.f + __expf(-x));
}
__device__ __forceinline__ unsigned short f2bf(float f) {
    union { float f; unsigned int u; } v; v.f = f;
    const unsigned int r = (v.u + 0x7FFFu + ((v.u >> 16) & 1u)) >> 16;
    return (unsigned short)r;
}

// ---------------------------------------------------------------------------
// fp32 -> bf16 conversion, 8 elems/thread, n must be %8
// ---------------------------------------------------------------------------
__global__ __launch_bounds__(256)
void cvt_f32_bf16(const float* __restrict__ in, unsigned short* __restrict__ out,
                  int n8) {
    const int i = blockIdx.x * 256 + threadIdx.x;
    if (i < n8) {
        const float4 a = reinterpret_cast<const float4*>(in)[i * 2 + 0];
        const float4 b = reinterpret_cast<const float4*>(in)[i * 2 + 1];
        ushort4 o0, o1;
        o0.x = f2bf(a.x); o0.y = f2bf(a.y); o0.z = f2bf(a.z); o0.w = f2bf(a.w);
        o1.x = f2bf(b.x); o1.y = f2bf(b.y); o1.z = f2bf(b.z); o1.w = f2bf(b.w);
        reinterpret_cast<ushort4*>(out)[i * 2 + 0] = o0;
        reinterpret_cast<ushort4*>(out)[i * 2 + 1] = o1;
    }
}

// ---------------------------------------------------------------------------
// bf16 MFMA GEMM (m97-style): C[M][N] = A[M][K] @ W[N][K]^T
// 128x128 tile, BK=32, 256 threads = 4 waves (2x2 of 64x64), 16x16x32 MFMA.
// global_load_lds(16B) staging into linear [m][k] LDS.
// EPI 0: fp32 store; EPI 2: fp32 store + res; EPI 3: bf16 store.
// Requires M%128==0, N%128==0, K%32==0 (true for all uses).
// ---------------------------------------------------------------------------
template <int EPI>
__global__ __launch_bounds__(256)
void gemm_bf16(const unsigned short* __restrict__ Ab, int lda,
               const unsigned short* __restrict__ Wb, int ldw,
               void* __restrict__ Cptr, int ldc, int K,
               const float* __restrict__ res, int ldr) {
    __shared__ unsigned short As[128 * 32];
    __shared__ unsigned short Bs[128 * 32];
    const int tid = threadIdx.x;
    const int wave = tid >> 6, lane = tid & 63;
    const int wr = wave >> 1, wc = wave & 1;
    const int m0 = blockIdx.y * 128, n0 = blockIdx.x * 128;
    const int r = lane & 15, kq = lane >> 4;

    f32x4 acc[4][4] = {};

    for (int kt = 0; kt < K; kt += 32) {
#pragma unroll
        for (int i = 0; i < 2; ++i) {
            const int chunk = i * 256 + tid;
            const int m = chunk >> 2, kc = chunk & 3;
            __builtin_amdgcn_global_load_lds(
                (const __attribute__((address_space(1))) void*)
                    &Ab[(size_t)(m0 + m) * lda + kt + kc * 8],
                (__attribute__((address_space(3))) void*)&As[chunk * 8], 16, 0, 0);
            __builtin_amdgcn_global_load_lds(
                (const __attribute__((address_space(1))) void*)
                    &Wb[(size_t)(n0 + m) * ldw + kt + kc * 8],
                (__attribute__((address_space(3))) void*)&Bs[chunk * 8], 16, 0, 0);
        }
        __syncthreads();
        bf16x8 a[4], b[4];
#pragma unroll
        for (int f = 0; f < 4; ++f) {
            a[f] = *reinterpret_cast<const bf16x8*>(&As[(wr * 64 + f * 16 + r) * 32 + kq * 8]);
            b[f] = *reinterpret_cast<const bf16x8*>(&Bs[(wc * 64 + f * 16 + r) * 32 + kq * 8]);
        }
#pragma unroll
        for (int fi = 0; fi < 4; ++fi)
#pragma unroll
            for (int fj = 0; fj < 4; ++fj)
                acc[fi][fj] = __builtin_amdgcn_mfma_f32_16x16x32_bf16(
                    a[fi], b[fj], acc[fi][fj], 0, 0, 0);
        __syncthreads();
    }

    // Epilogue. C/D layout: col = lane&15, row = (lane>>4)*4 + reg (m89).
    const int cr = lane >> 4, cc = lane & 15;
#pragma unroll
    for (int fi = 0; fi < 4; ++fi)
#pragma unroll
        for (int fj = 0; fj < 4; ++fj)
#pragma unroll
            for (int p = 0; p < 4; ++p) {
                const int m = m0 + wr * 64 + fi * 16 + cr * 4 + p;
                const int n = n0 + wc * 64 + fj * 16 + cc;
                const float v = acc[fi][fj][p];
                if (EPI == 0) {
                    ((float*)Cptr)[(size_t)m * ldc + n] = v;
                } else if (EPI == 2) {
                    ((float*)Cptr)[(size_t)m * ldc + n] = v + res[(size_t)m * ldr + n];
                } else {  // EPI 3: bf16 store
                    ((unsigned short*)Cptr)[(size_t)m * ldc + n] = f2bf(v);
                }
            }
}

// ---------------------------------------------------------------------------
// Tiled fp32 GEMM (kept for x_proj / dt_proj):  C = A @ W^T (+ epilogue)
// EPI 0: plain store; EPI 1: softplus(acc+bias[n]).
// Optional K-split via blockIdx.z.
// ---------------------------------------------------------------------------
template <int EPI>
__global__ __launch_bounds__(256)
void gemm128(const float* __restrict__ A, int lda,
             const float* __restrict__ W, int ldw,
             float* __restrict__ C, int ldc,
             int M, int N, int kLen, size_t cSlice,
             const float* __restrict__ bias) {
    constexpr int BK = 16;
    __shared__ float As[BK][128];
    __shared__ float Bs[BK][128];

    const int tid = threadIdx.x;
    const int tx = tid & 15;
    const int ty = tid >> 4;
    const int m0 = blockIdx.y * 128;
    const int n0 = blockIdx.x * 128;
    const int kbeg = blockIdx.z * kLen;
    const int kend = kbeg + kLen;
    C += (size_t)blockIdx.z * cSlice;

    const int r0 = tid >> 2;
    const int kv = tid & 3;

    float acc[8][8];
#pragma unroll
    for (int i = 0; i < 8; ++i)
#pragma unroll
        for (int j = 0; j < 8; ++j) acc[i][j] = 0.f;

    for (int kt = kbeg; kt < kend; kt += BK) {
#pragma unroll
        for (int rep = 0; rep < 2; ++rep) {
            const int r = r0 + rep * 64;
            const float4 a4 = *reinterpret_cast<const float4*>(
                &A[(size_t)(m0 + r) * lda + kt + kv * 4]);
            As[kv * 4 + 0][r] = a4.x;
            As[kv * 4 + 1][r] = a4.y;
            As[kv * 4 + 2][r] = a4.z;
            As[kv * 4 + 3][r] = a4.w;
            float4 b4 = make_float4(0.f, 0.f, 0.f, 0.f);
            const int n = n0 + r;
            if (n < N)
                b4 = *reinterpret_cast<const float4*>(
                    &W[(size_t)n * ldw + kt + kv * 4]);
            Bs[kv * 4 + 0][r] = b4.x;
            Bs[kv * 4 + 1][r] = b4.y;
            Bs[kv * 4 + 2][r] = b4.z;
            Bs[kv * 4 + 3][r] = b4.w;
        }
        __syncthreads();
#pragma unroll
        for (int kk = 0; kk < BK; ++kk) {
            const float4 a0 = *reinterpret_cast<const float4*>(&As[kk][ty * 8 + 0]);
            const float4 a1 = *reinterpret_cast<const float4*>(&As[kk][ty * 8 + 4]);
            const float4 b0 = *reinterpret_cast<const float4*>(&Bs[kk][tx * 8 + 0]);
            const float4 b1 = *reinterpret_cast<const float4*>(&Bs[kk][tx * 8 + 4]);
            const float av[8] = {a0.x, a0.y, a0.z, a0.w, a1.x, a1.y, a1.z, a1.w};
            const float bv[8] = {b0.x, b0.y, b0.z, b0.w, b1.x, b1.y, b1.z, b1.w};
#pragma unroll
            for (int i = 0; i < 8; ++i)
#pragma unroll
                for (int j = 0; j < 8; ++j)
                    acc[i][j] = fmaf(av[i], bv[j], acc[i][j]);
        }
        __syncthreads();
    }

#pragma unroll
    for (int i = 0; i < 8; ++i) {
        const int m = m0 + ty * 8 + i;
#pragma unroll
        for (int jv = 0; jv < 2; ++jv) {
            const int n = n0 + tx * 8 + jv * 4;
            if (n < N) {
                float4 v;
                v.x = acc[i][jv * 4 + 0];
                v.y = acc[i][jv * 4 + 1];
                v.z = acc[i][jv * 4 + 2];
                v.w = acc[i][jv * 4 + 3];
                if (EPI == 1) {
                    v.x = softplusf(v.x + bias[n + 0]);
                    v.y = softplusf(v.y + bias[n + 1]);
                    v.z = softplusf(v.z + bias[n + 2]);
                    v.w = softplusf(v.w + bias[n + 3]);
                }
                *reinterpret_cast<float4*>(&C[(size_t)m * ldc + n]) = v;
            }
        }
    }
}

// Sum KSPLIT partial GEMM outputs.
__global__ __launch_bounds__(256)
void reduce_ksplit(const float* __restrict__ part, float* __restrict__ out,
                   int n, size_t stride) {
    const int i = blockIdx.x * 256 + threadIdx.x;
    if (i < n) {
        float s = 0.f;
#pragma unroll
        for (int k = 0; k < KSPLIT; ++k) s += part[(size_t)k * stride + i];
        out[i] = s;
    }
}

// ---------------------------------------------------------------------------
// Causal depthwise conv1d (+bias) + SiLU.
// ---------------------------------------------------------------------------
__global__ __launch_bounds__(256)
void conv_silu(const float* __restrict__ xz,
               const float* __restrict__ cw,
               const float* __restrict__ cb,
               float* __restrict__ u) {
    const int idx = blockIdx.x * 256 + threadIdx.x;
    const int d = idx & (DINNER - 1);
    const int token = idx >> 11;
    const int l = token & (SEQ - 1);
    float acc = cb[d];
#pragma unroll
    for (int k = 0; k < DCONV; ++k) {
        const int li = l - (DCONV - 1) + k;
        if (li >= 0)
            acc = fmaf(cw[d * DCONV + k],
                       xz[(size_t)(token - (DCONV - 1) + k) * (2 * DINNER) + d],
                       acc);
    }
    u[idx] = siluf(acc);
}

// ---------------------------------------------------------------------------
// Chunk-parallel selective scan (3 passes).
// ---------------------------------------------------------------------------
__global__ __launch_bounds__(256)
void scan_partial(const float* __restrict__ delta,
                  const float* __restrict__ u,
                  const float* __restrict__ xdbl,
                  const float* __restrict__ A_log,
                  float* __restrict__ hbuf,
                  float* __restrict__ Pbuf) {
    const int b = blockIdx.y / NCHUNK;
    const int c = blockIdx.y % NCHUNK;
    const int d = blockIdx.x * 16 + (threadIdx.x >> 4);
    const int n = threadIdx.x & 15;

    const float A_dn = -__expf(A_log[d * DSTATE + n]);
    float h = 0.f, P = 1.f;
    const int t0 = b * SEQ + c * CLEN;
#pragma unroll 4
    for (int l = 0; l < CLEN; ++l) {
        const int t = t0 + l;
        const float dlt = delta[(size_t)t * DINNER + d];
        const float uv = u[(size_t)t * DINNER + d];
        const float Bv = xdbl[(size_t)t * 96 + DTRANK + n];
        const float dA = __expf(dlt * A_dn);
        h = fmaf(dA, h, dlt * Bv * uv);
        P *= dA;
    }
    const size_t idx = ((size_t)(b * NCHUNK + c) * DINNER + d) * DSTATE + n;
    hbuf[idx] = h;
    Pbuf[idx] = P;
}

__global__ __launch_bounds__(256)
void scan_combine(float* __restrict__ hbuf, const float* __restrict__ Pbuf) {
    const int gid = blockIdx.x * 256 + threadIdx.x;
    const int b = gid / (DINNER * DSTATE);
    const int dn = gid - b * (DINNER * DSTATE);
    const size_t base = (size_t)b * NCHUNK * DINNER * DSTATE + dn;
    float hi = 0.f;
#pragma unroll
    for (int c = 0; c < NCHUNK; ++c) {
        const size_t idx = base + (size_t)c * (DINNER * DSTATE);
        const float hl = hbuf[idx];
        const float Pc = Pbuf[idx];
        hbuf[idx] = hi;
        hi = fmaf(Pc, hi, hl);
    }
}

__global__ __launch_bounds__(256)
void scan_final(const float* __restrict__ delta,
                const float* __restrict__ u,
                const float* __restrict__ xdbl,
                const float* __restrict__ xz,
                const float* __restrict__ A_log,
                const float* __restrict__ Dp,
                const float* __restrict__ hbuf,
                unsigned short* __restrict__ yout) {  // bf16 output
    const int b = blockIdx.y / NCHUNK;
    const int c = blockIdx.y % NCHUNK;
    const int d = blockIdx.x * 16 + (threadIdx.x >> 4);
    const int n = threadIdx.x & 15;

    const float A_dn = -__expf(A_log[d * DSTATE + n]);
    const float Dd = Dp[d];
    float h = hbuf[((size_t)(b * NCHUNK + c) * DINNER + d) * DSTATE + n];
    const int t0 = b * SEQ + c * CLEN;
#pragma unroll 2
    for (int l = 0; l < CLEN; ++l) {
        const int t = t0 + l;
        const float dlt = delta[(size_t)t * DINNER + d];
        const float uv = u[(size_t)t * DINNER + d];
        const float Bv = xdbl[(size_t)t * 96 + DTRANK + n];
        const float Cv = xdbl[(size_t)t * 96 + DTRANK + DSTATE + n];
        const float dA = __expf(dlt * A_dn);
        h = fmaf(dA, h, dlt * Bv * uv);
        float p = h * Cv;
        p += __shfl_xor(p, 1, 16);
        p += __shfl_xor(p, 2, 16);
        p += __shfl_xor(p, 4, 16);
        p += __shfl_xor(p, 8, 16);
        if (n == 0) {
            const float zv = xz[(size_t)t * (2 * DINNER) + DINNER + d];
            const float y = p + uv * Dd;
            yout[(size_t)t * DINNER + d] = f2bf(y * siluf(zv));
        }
    }
}

// ---------------------------------------------------------------------------
extern "C" void kernel_launch(void* const* d_in, const int* in_sizes, int n_in,
                              void* d_out, int out_size, void* d_ws, size_t ws_size,
                              hipStream_t stream) {
    const float* x          = (const float*)d_in[0];
    const float* in_proj_w  = (const float*)d_in[1];
    const float* conv_w     = (const float*)d_in[2];
    const float* conv_b     = (const float*)d_in[3];
    const float* x_proj_w   = (const float*)d_in[4];
    const float* dt_proj_w  = (const float*)d_in[5];
    const float* dt_proj_b  = (const float*)d_in[6];
    const float* A_log      = (const float*)d_in[7];
    const float* Dp         = (const float*)d_in[8];
    const float* out_proj_w = (const float*)d_in[9];
    float* out = (float*)d_out;

    // workspace layout
    float* ws = (float*)d_ws;
    float* xz    = ws;                          // TOK*4096
    float* u     = xz    + (size_t)TOK * 4096;  // TOK*2048
    float* xdbl  = u     + (size_t)TOK * 2048;  // TOK*96
    float* delta = xdbl  + (size_t)TOK * 96;    // TOK*2048
    float* xpart = delta + (size_t)TOK * 2048;  // KSPLIT*TOK*96
    float* hbuf  = xpart + (size_t)KSPLIT * TOK * 96;
    float* Pbuf  = hbuf  + (size_t)BATCH * NCHUNK * DINNER * DSTATE;
    unsigned short* bfbase = (unsigned short*)(Pbuf + (size_t)BATCH * NCHUNK * DINNER * DSTATE);
    unsigned short* wi_bf  = bfbase;                               // 4096*1024
    unsigned short* wo_bf  = wi_bf + (size_t)4096 * 1024;          // 1024*2048
    unsigned short* act_bf = wo_bf + (size_t)1024 * 2048;          // TOK*1024
    unsigned short* y_bf   = act_bf + (size_t)TOK * 1024;          // TOK*2048

    // layer-0 activation input -> bf16
    cvt_f32_bf16<<<(TOK * DMODEL / 8 + 255) / 256, 256, 0, stream>>>(
        x, act_bf, TOK * DMODEL / 8);

    for (int layer = 0; layer < NLAYERS; ++layer) {
        const float* Wi = in_proj_w  + (size_t)layer * (2 * DINNER) * DMODEL;
        const float* cw = conv_w     + (size_t)layer * DINNER * DCONV;
        const float* cb = conv_b     + (size_t)layer * DINNER;
        const float* Wx = x_proj_w   + (size_t)layer * 96 * DINNER;
        const float* Wd = dt_proj_w  + (size_t)layer * DINNER * DTRANK;
        const float* bd = dt_proj_b  + (size_t)layer * DINNER;
        const float* Al = A_log      + (size_t)layer * DINNER * DSTATE;
        const float* Dl = Dp         + (size_t)layer * DINNER;
        const float* Wo = out_proj_w + (size_t)layer * DMODEL * DINNER;

        // weights -> bf16
        cvt_f32_bf16<<<(2 * DINNER * DMODEL / 8 + 255) / 256, 256, 0, stream>>>(
            Wi, wi_bf, 2 * DINNER * DMODEL / 8);
        cvt_f32_bf16<<<(DMODEL * DINNER / 8 + 255) / 256, 256, 0, stream>>>(
            Wo, wo_bf, DMODEL * DINNER / 8);

        // 1. xz = act @ W_in^T   (TOK x 4096, K=1024)  [bf16 MFMA]
        {
            dim3 grid(4096 / 128, TOK / 128);
            gemm_bf16<0><<<grid, 256, 0, stream>>>(act_bf, DMODEL, wi_bf, DMODEL,
                                                   xz, 2 * DINNER, DMODEL,
                                                   nullptr, 0);
        }
        // 2. u = silu(causal depthwise conv(xc) + b)
        conv_silu<<<(TOK * DINNER) / 256, 256, 0, stream>>>(xz, cw, cb, u);
        // 3. x_dbl = u @ W_x^T (TOK x 96, K=2048), split-K (fp32)
        {
            dim3 grid(1, TOK / 128, KSPLIT);
            gemm128<0><<<grid, 256, 0, stream>>>(u, DINNER, Wx, DINNER,
                                                 xpart, 96, TOK, 96,
                                                 DINNER / KSPLIT, (size_t)TOK * 96,
                                                 nullptr);
            reduce_ksplit<<<(TOK * 96 + 255) / 256, 256, 0, stream>>>(
                xpart, xdbl, TOK * 96, (size_t)TOK * 96);
        }
        // 4. delta = softplus(dt @ W_dt^T + b_dt)  (fp32)
        {
            dim3 grid(DINNER / 128, TOK / 128, 1);
            gemm128<1><<<grid, 256, 0, stream>>>(xdbl, 96, Wd, DTRANK,
                                                 delta, DINNER, TOK, DINNER,
                                                 DTRANK, 0, bd);
        }
        // 5. chunk-parallel scan -> y (bf16)
        {
            dim3 gridA(DINNER / 16, BATCH * NCHUNK);
            scan_partial<<<gridA, 256, 0, stream>>>(delta, u, xdbl, Al, hbuf, Pbuf);
            scan_combine<<<(BATCH * DINNER * DSTATE) / 256, 256, 0, stream>>>(hbuf, Pbuf);
            scan_final<<<gridA, 256, 0, stream>>>(delta, u, xdbl, xz, Al, Dl, hbuf, y_bf);
        }
        // 6. out = y @ W_out^T  [bf16 MFMA]
        {
            dim3 grid(DMODEL / 128, TOK / 128);
            if (layer == NLAYERS - 1) {
                gemm_bf16<2><<<grid, 256, 0, stream>>>(y_bf, DINNER, wo_bf, DINNER,
                                                       out, DMODEL, DINNER,
                                                       x, DMODEL);
            } else {
                // write next layer's activation directly in bf16
                gemm_bf16<3><<<grid, 256, 0, stream>>>(y_bf, DINNER, wo_bf, DINNER,
                                                       act_bf, DMODEL, DINNER,
                                                       nullptr, 0);
            }
        }
    }
}

// Round 4
// 481.750 us; speedup vs baseline: 5.8634x; 1.3643x over previous
//
#include <hip/hip_runtime.h>
#include <hip/hip_bf16.h>

// Problem constants
#define NLAYERS 2
#define DMODEL 1024
#define DINNER 2048
#define DSTATE 16
#define DCONV 4
#define DTRANK 64
#define BATCH 2
#define SEQ 1024
#define TOK (BATCH * SEQ)   // 2048 tokens

#define NCHUNK 32
#define CLEN (SEQ / NCHUNK)  // 32
#define KSPLIT 8             // x_proj K-split

typedef short bf16x8 __attribute__((ext_vector_type(8)));
typedef float f32x4 __attribute__((ext_vector_type(4)));

__device__ __forceinline__ float softplusf(float x) {
    return (x > 20.f) ? x : log1pf(__expf(x));
}
__device__ __forceinline__ float siluf(float x) {
    return x / (1.f + __expf(-x));
}
__device__ __forceinline__ unsigned short f2bf(float f) {
    union { float f; unsigned int u; } v; v.f = f;
    const unsigned int r = (v.u + 0x7FFFu + ((v.u >> 16) & 1u)) >> 16;
    return (unsigned short)r;
}

// ---------------------------------------------------------------------------
// fp32 -> bf16 conversion, 8 elems/thread
// ---------------------------------------------------------------------------
__global__ __launch_bounds__(256)
void cvt_f32_bf16(const float* __restrict__ in, unsigned short* __restrict__ out,
                  int n8) {
    const int i = blockIdx.x * 256 + threadIdx.x;
    if (i < n8) {
        const float4 a = reinterpret_cast<const float4*>(in)[i * 2 + 0];
        const float4 b = reinterpret_cast<const float4*>(in)[i * 2 + 1];
        ushort4 o0, o1;
        o0.x = f2bf(a.x); o0.y = f2bf(a.y); o0.z = f2bf(a.z); o0.w = f2bf(a.w);
        o1.x = f2bf(b.x); o1.y = f2bf(b.y); o1.z = f2bf(b.z); o1.w = f2bf(b.w);
        reinterpret_cast<ushort4*>(out)[i * 2 + 0] = o0;
        reinterpret_cast<ushort4*>(out)[i * 2 + 1] = o1;
    }
}

// ---------------------------------------------------------------------------
// bf16 MFMA GEMM (m97-style): C[M][N] = A[M][K] @ W[N][K]^T
// EPI 0: fp32 store; EPI 2: fp32 store + res; EPI 3: bf16 store.
// ---------------------------------------------------------------------------
template <int EPI>
__global__ __launch_bounds__(256)
void gemm_bf16(const unsigned short* __restrict__ Ab, int lda,
               const unsigned short* __restrict__ Wb, int ldw,
               void* __restrict__ Cptr, int ldc, int K,
               const float* __restrict__ res, int ldr) {
    __shared__ unsigned short As[128 * 32];
    __shared__ unsigned short Bs[128 * 32];
    const int tid = threadIdx.x;
    const int wave = tid >> 6, lane = tid & 63;
    const int wr = wave >> 1, wc = wave & 1;
    const int m0 = blockIdx.y * 128, n0 = blockIdx.x * 128;
    const int r = lane & 15, kq = lane >> 4;

    f32x4 acc[4][4] = {};

    for (int kt = 0; kt < K; kt += 32) {
#pragma unroll
        for (int i = 0; i < 2; ++i) {
            const int chunk = i * 256 + tid;
            const int m = chunk >> 2, kc = chunk & 3;
            __builtin_amdgcn_global_load_lds(
                (const __attribute__((address_space(1))) void*)
                    &Ab[(size_t)(m0 + m) * lda + kt + kc * 8],
                (__attribute__((address_space(3))) void*)&As[chunk * 8], 16, 0, 0);
            __builtin_amdgcn_global_load_lds(
                (const __attribute__((address_space(1))) void*)
                    &Wb[(size_t)(n0 + m) * ldw + kt + kc * 8],
                (__attribute__((address_space(3))) void*)&Bs[chunk * 8], 16, 0, 0);
        }
        __syncthreads();
        bf16x8 a[4], b[4];
#pragma unroll
        for (int f = 0; f < 4; ++f) {
            a[f] = *reinterpret_cast<const bf16x8*>(&As[(wr * 64 + f * 16 + r) * 32 + kq * 8]);
            b[f] = *reinterpret_cast<const bf16x8*>(&Bs[(wc * 64 + f * 16 + r) * 32 + kq * 8]);
        }
#pragma unroll
        for (int fi = 0; fi < 4; ++fi)
#pragma unroll
            for (int fj = 0; fj < 4; ++fj)
                acc[fi][fj] = __builtin_amdgcn_mfma_f32_16x16x32_bf16(
                    a[fi], b[fj], acc[fi][fj], 0, 0, 0);
        __syncthreads();
    }

    const int cr = lane >> 4, cc = lane & 15;
#pragma unroll
    for (int fi = 0; fi < 4; ++fi)
#pragma unroll
        for (int fj = 0; fj < 4; ++fj)
#pragma unroll
            for (int p = 0; p < 4; ++p) {
                const int m = m0 + wr * 64 + fi * 16 + cr * 4 + p;
                const int n = n0 + wc * 64 + fj * 16 + cc;
                const float v = acc[fi][fj][p];
                if (EPI == 0) {
                    ((float*)Cptr)[(size_t)m * ldc + n] = v;
                } else if (EPI == 2) {
                    ((float*)Cptr)[(size_t)m * ldc + n] = v + res[(size_t)m * ldr + n];
                } else {  // EPI 3: bf16 store
                    ((unsigned short*)Cptr)[(size_t)m * ldc + n] = f2bf(v);
                }
            }
}

// ---------------------------------------------------------------------------
// Tiled fp32 GEMM (x_proj / dt_proj):  C = A @ W^T (+ epilogue)
// EPI 0: plain store; EPI 1: softplus(acc+bias[n]). K-split via blockIdx.z.
// ---------------------------------------------------------------------------
template <int EPI>
__global__ __launch_bounds__(256)
void gemm128(const float* __restrict__ A, int lda,
             const float* __restrict__ W, int ldw,
             float* __restrict__ C, int ldc,
             int M, int N, int kLen, size_t cSlice,
             const float* __restrict__ bias) {
    constexpr int BK = 16;
    __shared__ float As[BK][128];
    __shared__ float Bs[BK][128];

    const int tid = threadIdx.x;
    const int tx = tid & 15;
    const int ty = tid >> 4;
    const int m0 = blockIdx.y * 128;
    const int n0 = blockIdx.x * 128;
    const int kbeg = blockIdx.z * kLen;
    const int kend = kbeg + kLen;
    C += (size_t)blockIdx.z * cSlice;

    const int r0 = tid >> 2;
    const int kv = tid & 3;

    float acc[8][8];
#pragma unroll
    for (int i = 0; i < 8; ++i)
#pragma unroll
        for (int j = 0; j < 8; ++j) acc[i][j] = 0.f;

    for (int kt = kbeg; kt < kend; kt += BK) {
#pragma unroll
        for (int rep = 0; rep < 2; ++rep) {
            const int r = r0 + rep * 64;
            const float4 a4 = *reinterpret_cast<const float4*>(
                &A[(size_t)(m0 + r) * lda + kt + kv * 4]);
            As[kv * 4 + 0][r] = a4.x;
            As[kv * 4 + 1][r] = a4.y;
            As[kv * 4 + 2][r] = a4.z;
            As[kv * 4 + 3][r] = a4.w;
            float4 b4 = make_float4(0.f, 0.f, 0.f, 0.f);
            const int n = n0 + r;
            if (n < N)
                b4 = *reinterpret_cast<const float4*>(
                    &W[(size_t)n * ldw + kt + kv * 4]);
            Bs[kv * 4 + 0][r] = b4.x;
            Bs[kv * 4 + 1][r] = b4.y;
            Bs[kv * 4 + 2][r] = b4.z;
            Bs[kv * 4 + 3][r] = b4.w;
        }
        __syncthreads();
#pragma unroll
        for (int kk = 0; kk < BK; ++kk) {
            const float4 a0 = *reinterpret_cast<const float4*>(&As[kk][ty * 8 + 0]);
            const float4 a1 = *reinterpret_cast<const float4*>(&As[kk][ty * 8 + 4]);
            const float4 b0 = *reinterpret_cast<const float4*>(&Bs[kk][tx * 8 + 0]);
            const float4 b1 = *reinterpret_cast<const float4*>(&Bs[kk][tx * 8 + 4]);
            const float av[8] = {a0.x, a0.y, a0.z, a0.w, a1.x, a1.y, a1.z, a1.w};
            const float bv[8] = {b0.x, b0.y, b0.z, b0.w, b1.x, b1.y, b1.z, b1.w};
#pragma unroll
            for (int i = 0; i < 8; ++i)
#pragma unroll
                for (int j = 0; j < 8; ++j)
                    acc[i][j] = fmaf(av[i], bv[j], acc[i][j]);
        }
        __syncthreads();
    }

#pragma unroll
    for (int i = 0; i < 8; ++i) {
        const int m = m0 + ty * 8 + i;
#pragma unroll
        for (int jv = 0; jv < 2; ++jv) {
            const int n = n0 + tx * 8 + jv * 4;
            if (n < N) {
                float4 v;
                v.x = acc[i][jv * 4 + 0];
                v.y = acc[i][jv * 4 + 1];
                v.z = acc[i][jv * 4 + 2];
                v.w = acc[i][jv * 4 + 3];
                if (EPI == 1) {
                    v.x = softplusf(v.x + bias[n + 0]);
                    v.y = softplusf(v.y + bias[n + 1]);
                    v.z = softplusf(v.z + bias[n + 2]);
                    v.w = softplusf(v.w + bias[n + 3]);
                }
                *reinterpret_cast<float4*>(&C[(size_t)m * ldc + n]) = v;
            }
        }
    }
}

// Sum KSPLIT partial GEMM outputs.
__global__ __launch_bounds__(256)
void reduce_ksplit(const float* __restrict__ part, float* __restrict__ out,
                   int n, size_t stride) {
    const int i = blockIdx.x * 256 + threadIdx.x;
    if (i < n) {
        float s = 0.f;
#pragma unroll
        for (int k = 0; k < KSPLIT; ++k) s += part[(size_t)k * stride + i];
        out[i] = s;
    }
}

// ---------------------------------------------------------------------------
// Causal depthwise conv1d (+bias) + SiLU.
// ---------------------------------------------------------------------------
__global__ __launch_bounds__(256)
void conv_silu(const float* __restrict__ xz,
               const float* __restrict__ cw,
               const float* __restrict__ cb,
               float* __restrict__ u) {
    const int idx = blockIdx.x * 256 + threadIdx.x;
    const int d = idx & (DINNER - 1);
    const int token = idx >> 11;
    const int l = token & (SEQ - 1);
    float acc = cb[d];
#pragma unroll
    for (int k = 0; k < DCONV; ++k) {
        const int li = l - (DCONV - 1) + k;
        if (li >= 0)
            acc = fmaf(cw[d * DCONV + k],
                       xz[(size_t)(token - (DCONV - 1) + k) * (2 * DINNER) + d],
                       acc);
    }
    u[idx] = siluf(acc);
}

// ---------------------------------------------------------------------------
// Chunk-parallel selective scan, register-state version.
// One thread per channel d, all 16 states in registers.
// Grid: (DINNER/256, BATCH*NCHUNK), block 256.
// hbuf/Pbuf layout: [b][chunk][d][n], n contiguous.
// ---------------------------------------------------------------------------
__device__ __forceinline__ void load_b16(const float* __restrict__ p, float* B) {
    const float4* bp = reinterpret_cast<const float4*>(p);
    const float4 b0 = bp[0], b1 = bp[1], b2 = bp[2], b3 = bp[3];
    B[0] = b0.x; B[1] = b0.y; B[2] = b0.z; B[3] = b0.w;
    B[4] = b1.x; B[5] = b1.y; B[6] = b1.z; B[7] = b1.w;
    B[8] = b2.x; B[9] = b2.y; B[10] = b2.z; B[11] = b2.w;
    B[12] = b3.x; B[13] = b3.y; B[14] = b3.z; B[15] = b3.w;
}

__global__ __launch_bounds__(256)
void scan_partial(const float* __restrict__ delta,
                  const float* __restrict__ u,
                  const float* __restrict__ xdbl,
                  const float* __restrict__ A_log,
                  float* __restrict__ hbuf,
                  float* __restrict__ Pbuf) {
    const int b = blockIdx.y / NCHUNK;
    const int c = blockIdx.y % NCHUNK;
    const int d = blockIdx.x * 256 + threadIdx.x;
    const int t0 = b * SEQ + c * CLEN;

    float A_dn[16];
    load_b16(&A_log[d * DSTATE], A_dn);
#pragma unroll
    for (int n = 0; n < 16; ++n) A_dn[n] = -__expf(A_dn[n]);

    float h[16], P[16];
#pragma unroll
    for (int n = 0; n < 16; ++n) { h[n] = 0.f; P[n] = 1.f; }

    float dltA, uvA, BA[16];
    float dltB, uvB, BB[16];
    dltA = delta[(size_t)t0 * DINNER + d];
    uvA = u[(size_t)t0 * DINNER + d];
    load_b16(&xdbl[(size_t)t0 * 96 + DTRANK], BA);

#define PSTEP(dlt_, uv_, Bc_)                              \
    {                                                      \
        const float du = (dlt_) * (uv_);                   \
        _Pragma("unroll")                                  \
        for (int n = 0; n < 16; ++n) {                     \
            const float dA = __expf((dlt_) * A_dn[n]);     \
            h[n] = fmaf(dA, h[n], du * Bc_[n]);            \
            P[n] *= dA;                                    \
        }                                                  \
    }

    for (int l = 0; l < CLEN; l += 2) {
        const int t = t0 + l;
        // prefetch l+1 (always valid: l+1 <= CLEN-1)
        dltB = delta[(size_t)(t + 1) * DINNER + d];
        uvB = u[(size_t)(t + 1) * DINNER + d];
        load_b16(&xdbl[(size_t)(t + 1) * 96 + DTRANK], BB);
        PSTEP(dltA, uvA, BA);
        if (l + 2 < CLEN) {
            dltA = delta[(size_t)(t + 2) * DINNER + d];
            uvA = u[(size_t)(t + 2) * DINNER + d];
            load_b16(&xdbl[(size_t)(t + 2) * 96 + DTRANK], BA);
        }
        PSTEP(dltB, uvB, BB);
    }
#undef PSTEP

    float* hp = &hbuf[((size_t)(b * NCHUNK + c) * DINNER + d) * DSTATE];
    float* Pp = &Pbuf[((size_t)(b * NCHUNK + c) * DINNER + d) * DSTATE];
#pragma unroll
    for (int q = 0; q < 4; ++q) {
        reinterpret_cast<float4*>(hp)[q] = make_float4(h[q*4], h[q*4+1], h[q*4+2], h[q*4+3]);
        reinterpret_cast<float4*>(Pp)[q] = make_float4(P[q*4], P[q*4+1], P[q*4+2], P[q*4+3]);
    }
}

__global__ __launch_bounds__(256)
void scan_combine(float* __restrict__ hbuf, const float* __restrict__ Pbuf) {
    const int gid = blockIdx.x * 256 + threadIdx.x;  // over BATCH*DINNER*DSTATE
    const int b = gid / (DINNER * DSTATE);
    const int dn = gid - b * (DINNER * DSTATE);
    const size_t base = (size_t)b * NCHUNK * DINNER * DSTATE + dn;
    float hi = 0.f;
#pragma unroll
    for (int c = 0; c < NCHUNK; ++c) {
        const size_t idx = base + (size_t)c * (DINNER * DSTATE);
        const float hl = hbuf[idx];
        const float Pc = Pbuf[idx];
        hbuf[idx] = hi;
        hi = fmaf(Pc, hi, hl);
    }
}

__global__ __launch_bounds__(256)
void scan_final(const float* __restrict__ delta,
                const float* __restrict__ u,
                const float* __restrict__ xdbl,
                const float* __restrict__ xz,
                const float* __restrict__ A_log,
                const float* __restrict__ Dp,
                const float* __restrict__ hbuf,
                unsigned short* __restrict__ yout) {  // bf16 output
    const int b = blockIdx.y / NCHUNK;
    const int c = blockIdx.y % NCHUNK;
    const int d = blockIdx.x * 256 + threadIdx.x;
    const int t0 = b * SEQ + c * CLEN;

    float A_dn[16];
    load_b16(&A_log[d * DSTATE], A_dn);
#pragma unroll
    for (int n = 0; n < 16; ++n) A_dn[n] = -__expf(A_dn[n]);
    const float Dd = Dp[d];

    float h[16];
    load_b16(&hbuf[((size_t)(b * NCHUNK + c) * DINNER + d) * DSTATE], h);

    float dltA, uvA, BA[16], CA[16];
    float dltB, uvB, BB[16], CB[16];
    dltA = delta[(size_t)t0 * DINNER + d];
    uvA = u[(size_t)t0 * DINNER + d];
    load_b16(&xdbl[(size_t)t0 * 96 + DTRANK], BA);
    load_b16(&xdbl[(size_t)t0 * 96 + DTRANK + DSTATE], CA);

#define FSTEP(t_, dlt_, uv_, Bc_, Cc_)                          \
    {                                                           \
        const float du = (dlt_) * (uv_);                        \
        _Pragma("unroll")                                       \
        for (int n = 0; n < 16; ++n) {                          \
            const float dA = __expf((dlt_) * A_dn[n]);          \
            h[n] = fmaf(dA, h[n], du * Bc_[n]);                 \
        }                                                       \
        float s0 = 0.f, s1 = 0.f, s2 = 0.f, s3 = 0.f;           \
        _Pragma("unroll")                                       \
        for (int q = 0; q < 4; ++q) {                           \
            s0 = fmaf(h[q*4+0], Cc_[q*4+0], s0);                \
            s1 = fmaf(h[q*4+1], Cc_[q*4+1], s1);                \
            s2 = fmaf(h[q*4+2], Cc_[q*4+2], s2);                \
            s3 = fmaf(h[q*4+3], Cc_[q*4+3], s3);                \
        }                                                       \
        const float zv = xz[(size_t)(t_) * (2 * DINNER) + DINNER + d]; \
        const float y = (s0 + s1) + (s2 + s3) + (uv_) * Dd;     \
        yout[(size_t)(t_) * DINNER + d] = f2bf(y * siluf(zv));  \
    }

    for (int l = 0; l < CLEN; l += 2) {
        const int t = t0 + l;
        dltB = delta[(size_t)(t + 1) * DINNER + d];
        uvB = u[(size_t)(t + 1) * DINNER + d];
        load_b16(&xdbl[(size_t)(t + 1) * 96 + DTRANK], BB);
        load_b16(&xdbl[(size_t)(t + 1) * 96 + DTRANK + DSTATE], CB);
        FSTEP(t, dltA, uvA, BA, CA);
        if (l + 2 < CLEN) {
            dltA = delta[(size_t)(t + 2) * DINNER + d];
            uvA = u[(size_t)(t + 2) * DINNER + d];
            load_b16(&xdbl[(size_t)(t + 2) * 96 + DTRANK], BA);
            load_b16(&xdbl[(size_t)(t + 2) * 96 + DTRANK + DSTATE], CA);
        }
        FSTEP(t + 1, dltB, uvB, BB, CB);
    }
#undef FSTEP
}

// ---------------------------------------------------------------------------
extern "C" void kernel_launch(void* const* d_in, const int* in_sizes, int n_in,
                              void* d_out, int out_size, void* d_ws, size_t ws_size,
                              hipStream_t stream) {
    const float* x          = (const float*)d_in[0];
    const float* in_proj_w  = (const float*)d_in[1];
    const float* conv_w     = (const float*)d_in[2];
    const float* conv_b     = (const float*)d_in[3];
    const float* x_proj_w   = (const float*)d_in[4];
    const float* dt_proj_w  = (const float*)d_in[5];
    const float* dt_proj_b  = (const float*)d_in[6];
    const float* A_log      = (const float*)d_in[7];
    const float* Dp         = (const float*)d_in[8];
    const float* out_proj_w = (const float*)d_in[9];
    float* out = (float*)d_out;

    // workspace layout
    float* ws = (float*)d_ws;
    float* xz    = ws;                          // TOK*4096
    float* u     = xz    + (size_t)TOK * 4096;  // TOK*2048
    float* xdbl  = u     + (size_t)TOK * 2048;  // TOK*96
    float* delta = xdbl  + (size_t)TOK * 96;    // TOK*2048
    // scratch: xpart and hbuf/Pbuf have disjoint lifetimes -> alias
    float* scratch = delta + (size_t)TOK * 2048;
    float* xpart = scratch;                               // KSPLIT*TOK*96
    float* hbuf  = scratch;                               // B*NC*D*N
    float* Pbuf  = hbuf + (size_t)BATCH * NCHUNK * DINNER * DSTATE;
    const size_t scratch_sz = 2 * (size_t)BATCH * NCHUNK * DINNER * DSTATE; // > KSPLIT*TOK*96
    unsigned short* bfbase = (unsigned short*)(scratch + scratch_sz);
    unsigned short* wi_bf  = bfbase;                               // 4096*1024
    unsigned short* wo_bf  = wi_bf + (size_t)4096 * 1024;          // 1024*2048
    unsigned short* act_bf = wo_bf + (size_t)1024 * 2048;          // TOK*1024
    unsigned short* y_bf   = act_bf + (size_t)TOK * 1024;          // TOK*2048

    // layer-0 activation input -> bf16
    cvt_f32_bf16<<<(TOK * DMODEL / 8 + 255) / 256, 256, 0, stream>>>(
        x, act_bf, TOK * DMODEL / 8);

    for (int layer = 0; layer < NLAYERS; ++layer) {
        const float* Wi = in_proj_w  + (size_t)layer * (2 * DINNER) * DMODEL;
        const float* cw = conv_w     + (size_t)layer * DINNER * DCONV;
        const float* cb = conv_b     + (size_t)layer * DINNER;
        const float* Wx = x_proj_w   + (size_t)layer * 96 * DINNER;
        const float* Wd = dt_proj_w  + (size_t)layer * DINNER * DTRANK;
        const float* bd = dt_proj_b  + (size_t)layer * DINNER;
        const float* Al = A_log      + (size_t)layer * DINNER * DSTATE;
        const float* Dl = Dp         + (size_t)layer * DINNER;
        const float* Wo = out_proj_w + (size_t)layer * DMODEL * DINNER;

        // weights -> bf16
        cvt_f32_bf16<<<(2 * DINNER * DMODEL / 8 + 255) / 256, 256, 0, stream>>>(
            Wi, wi_bf, 2 * DINNER * DMODEL / 8);
        cvt_f32_bf16<<<(DMODEL * DINNER / 8 + 255) / 256, 256, 0, stream>>>(
            Wo, wo_bf, DMODEL * DINNER / 8);

        // 1. xz = act @ W_in^T   (TOK x 4096, K=1024)  [bf16 MFMA]
        {
            dim3 grid(4096 / 128, TOK / 128);
            gemm_bf16<0><<<grid, 256, 0, stream>>>(act_bf, DMODEL, wi_bf, DMODEL,
                                                   xz, 2 * DINNER, DMODEL,
                                                   nullptr, 0);
        }
        // 2. u = silu(causal depthwise conv(xc) + b)
        conv_silu<<<(TOK * DINNER) / 256, 256, 0, stream>>>(xz, cw, cb, u);
        // 3. x_dbl = u @ W_x^T (TOK x 96, K=2048), split-K (fp32)
        {
            dim3 grid(1, TOK / 128, KSPLIT);
            gemm128<0><<<grid, 256, 0, stream>>>(u, DINNER, Wx, DINNER,
                                                 xpart, 96, TOK, 96,
                                                 DINNER / KSPLIT, (size_t)TOK * 96,
                                                 nullptr);
            reduce_ksplit<<<(TOK * 96 + 255) / 256, 256, 0, stream>>>(
                xpart, xdbl, TOK * 96, (size_t)TOK * 96);
        }
        // 4. delta = softplus(dt @ W_dt^T + b_dt)  (fp32)
        {
            dim3 grid(DINNER / 128, TOK / 128, 1);
            gemm128<1><<<grid, 256, 0, stream>>>(xdbl, 96, Wd, DTRANK,
                                                 delta, DINNER, TOK, DINNER,
                                                 DTRANK, 0, bd);
        }
        // 5. chunk-parallel scan -> y (bf16)
        {
            dim3 gridA(DINNER / 256, BATCH * NCHUNK);
            scan_partial<<<gridA, 256, 0, stream>>>(delta, u, xdbl, Al, hbuf, Pbuf);
            scan_combine<<<(BATCH * DINNER * DSTATE) / 256, 256, 0, stream>>>(hbuf, Pbuf);
            scan_final<<<gridA, 256, 0, stream>>>(delta, u, xdbl, xz, Al, Dl, hbuf, y_bf);
        }
        // 6. out = y @ W_out^T  [bf16 MFMA]
        {
            dim3 grid(DMODEL / 128, TOK / 128);
            if (layer == NLAYERS - 1) {
                gemm_bf16<2><<<grid, 256, 0, stream>>>(y_bf, DINNER, wo_bf, DINNER,
                                                       out, DMODEL, DINNER,
                                                       x, DMODEL);
            } else {
                gemm_bf16<3><<<grid, 256, 0, stream>>>(y_bf, DINNER, wo_bf, DINNER,
                                                       act_bf, DMODEL, DINNER,
                                                       nullptr, 0);
            }
        }
    }
}

// Round 5
// 354.090 us; speedup vs baseline: 7.9774x; 1.3605x over previous
//
#include <hip/hip_runtime.h>
#include <hip/hip_bf16.h>

// Problem constants
#define NLAYERS 2
#define DMODEL 1024
#define DINNER 2048
#define DSTATE 16
#define DCONV 4
#define DTRANK 64
#define BATCH 2
#define SEQ 1024
#define TOK (BATCH * SEQ)   // 2048 tokens

#define NCHUNK 32
#define CLEN (SEQ / NCHUNK)  // 32
#define KSX 8                // x_proj K-split
#define KSO 4                // out_proj K-split

typedef short bf16x8 __attribute__((ext_vector_type(8)));
typedef float f32x4 __attribute__((ext_vector_type(4)));

__device__ __forceinline__ float softplusf(float x) {
    return (x > 20.f) ? x : log1pf(__expf(x));
}
__device__ __forceinline__ float siluf(float x) {
    return x / (1.f + __expf(-x));
}
__device__ __forceinline__ unsigned short f2bf(float f) {
    union { float f; unsigned int u; } v; v.f = f;
    const unsigned int r = (v.u + 0x7FFFu + ((v.u >> 16) & 1u)) >> 16;
    return (unsigned short)r;
}
__device__ __forceinline__ float bf2f(unsigned short s) {
    union { unsigned int u; float f; } v; v.u = ((unsigned int)s) << 16;
    return v.f;
}

// ---------------------------------------------------------------------------
// fp32 -> bf16, 8 elems/thread (helper)
// ---------------------------------------------------------------------------
__device__ __forceinline__ void cvt8(const float* __restrict__ in,
                                     unsigned short* __restrict__ out, int i) {
    const float4 a = reinterpret_cast<const float4*>(in)[i * 2 + 0];
    const float4 b = reinterpret_cast<const float4*>(in)[i * 2 + 1];
    ushort4 o0, o1;
    o0.x = f2bf(a.x); o0.y = f2bf(a.y); o0.z = f2bf(a.z); o0.w = f2bf(a.w);
    o1.x = f2bf(b.x); o1.y = f2bf(b.y); o1.z = f2bf(b.z); o1.w = f2bf(b.w);
    reinterpret_cast<ushort4*>(out)[i * 2 + 0] = o0;
    reinterpret_cast<ushort4*>(out)[i * 2 + 1] = o1;
}

__global__ __launch_bounds__(256)
void cvt_f32_bf16(const float* __restrict__ in, unsigned short* __restrict__ out,
                  int n8) {
    const int i = blockIdx.x * 256 + threadIdx.x;
    if (i < n8) cvt8(in, out, i);
}

// All weights (both layers) -> bf16 in one launch.
#define WI8 1048576  // 2*4096*1024/8
#define WO8 524288   // 2*1024*2048/8
#define WX8 49152    // 2*96*2048/8
#define WD8 32768    // 2*2048*64/8
__global__ __launch_bounds__(256)
void cvt_weights(const float* __restrict__ wi, const float* __restrict__ wo,
                 const float* __restrict__ wx, const float* __restrict__ wd,
                 unsigned short* __restrict__ wi_bf, unsigned short* __restrict__ wo_bf,
                 unsigned short* __restrict__ wx_bf, unsigned short* __restrict__ wd_bf) {
    int i = blockIdx.x * 256 + threadIdx.x;
    if (i < WI8) { cvt8(wi, wi_bf, i); return; }
    i -= WI8;
    if (i < WO8) { cvt8(wo, wo_bf, i); return; }
    i -= WO8;
    if (i < WX8) { cvt8(wx, wx_bf, i); return; }
    i -= WX8;
    if (i < WD8) { cvt8(wd, wd_bf, i); return; }
}

// ---------------------------------------------------------------------------
// bf16 MFMA GEMM (m97-style): C[M][N] = A[M][K] @ W[N][K]^T
// 128x128 tile, BK=32, 4 waves, 16x16x32 MFMA, global_load_lds(16B).
// Split-K: blockIdx.z picks K-slice [z*kLen, (z+1)*kLen); C += z*cSlice.
// Nw: valid W rows (source row clamped, EPI0 stores guarded n<Nw).
// EPI 0: fp32 store (guarded); EPI 1: fp32 softplus(acc+bias[n]); EPI 3: bf16.
// ---------------------------------------------------------------------------
template <int EPI>
__global__ __launch_bounds__(256)
void gemm_bf16(const unsigned short* __restrict__ Ab, int lda,
               const unsigned short* __restrict__ Wb, int ldw,
               void* __restrict__ Cptr, int ldc, int kLen, int Nw,
               size_t cSlice, const float* __restrict__ bias) {
    __shared__ unsigned short As[128 * 32];
    __shared__ unsigned short Bs[128 * 32];
    const int tid = threadIdx.x;
    const int wave = tid >> 6, lane = tid & 63;
    const int wr = wave >> 1, wc = wave & 1;
    const int m0 = blockIdx.y * 128, n0 = blockIdx.x * 128;
    const int kbeg = blockIdx.z * kLen;
    const int r = lane & 15, kq = lane >> 4;

    f32x4 acc[4][4] = {};

    for (int kt = kbeg; kt < kbeg + kLen; kt += 32) {
#pragma unroll
        for (int i = 0; i < 2; ++i) {
            const int chunk = i * 256 + tid;
            const int m = chunk >> 2, kc = chunk & 3;
            __builtin_amdgcn_global_load_lds(
                (const __attribute__((address_space(1))) void*)
                    &Ab[(size_t)(m0 + m) * lda + kt + kc * 8],
                (__attribute__((address_space(3))) void*)&As[chunk * 8], 16, 0, 0);
            const int wrow = min(n0 + m, Nw - 1);
            __builtin_amdgcn_global_load_lds(
                (const __attribute__((address_space(1))) void*)
                    &Wb[(size_t)wrow * ldw + kt + kc * 8],
                (__attribute__((address_space(3))) void*)&Bs[chunk * 8], 16, 0, 0);
        }
        __syncthreads();
        bf16x8 a[4], b[4];
#pragma unroll
        for (int f = 0; f < 4; ++f) {
            a[f] = *reinterpret_cast<const bf16x8*>(&As[(wr * 64 + f * 16 + r) * 32 + kq * 8]);
            b[f] = *reinterpret_cast<const bf16x8*>(&Bs[(wc * 64 + f * 16 + r) * 32 + kq * 8]);
        }
#pragma unroll
        for (int fi = 0; fi < 4; ++fi)
#pragma unroll
            for (int fj = 0; fj < 4; ++fj)
                acc[fi][fj] = __builtin_amdgcn_mfma_f32_16x16x32_bf16(
                    a[fi], b[fj], acc[fi][fj], 0, 0, 0);
        __syncthreads();
    }

    // C/D layout: col = lane&15, row = (lane>>4)*4 + reg (m89).
    const int cr = lane >> 4, cc = lane & 15;
#pragma unroll
    for (int fi = 0; fi < 4; ++fi)
#pragma unroll
        for (int fj = 0; fj < 4; ++fj)
#pragma unroll
            for (int p = 0; p < 4; ++p) {
                const int m = m0 + wr * 64 + fi * 16 + cr * 4 + p;
                const int n = n0 + wc * 64 + fj * 16 + cc;
                const float v = acc[fi][fj][p];
                if (EPI == 0) {
                    if (n < Nw)
                        ((float*)Cptr)[(size_t)blockIdx.z * cSlice +
                                       (size_t)m * ldc + n] = v;
                } else if (EPI == 1) {
                    ((float*)Cptr)[(size_t)m * ldc + n] = softplusf(v + bias[n]);
                } else {  // EPI 3: bf16 store
                    ((unsigned short*)Cptr)[(size_t)blockIdx.z * cSlice +
                                            (size_t)m * ldc + n] = f2bf(v);
                }
            }
}

// ---------------------------------------------------------------------------
// Reduce x_proj K-split partials -> xdbl fp32 [TOK][96] + dt_bf [TOK][64]
// ---------------------------------------------------------------------------
__global__ __launch_bounds__(256)
void reduce_x(const float* __restrict__ part, float* __restrict__ xdbl,
              unsigned short* __restrict__ dt_bf) {
    const int i = blockIdx.x * 256 + threadIdx.x;  // over TOK*96
    if (i >= TOK * 96) return;
    float s = 0.f;
#pragma unroll
    for (int k = 0; k < KSX; ++k) s += part[(size_t)k * (TOK * 96) + i];
    xdbl[i] = s;
    const int t = i / 96, c = i - t * 96;
    if (c < DTRANK) dt_bf[t * DTRANK + c] = f2bf(s);
}

// ---------------------------------------------------------------------------
// Reduce out_proj K-split bf16 partials (4 elems/thread).
// MODE 0: -> bf16 activation (next layer input)
// MODE 1: -> fp32 out + residual x
// ---------------------------------------------------------------------------
template <int MODE>
__global__ __launch_bounds__(256)
void reduce_out(const unsigned short* __restrict__ part,
                const float* __restrict__ resid, void* __restrict__ outp) {
    const int i = blockIdx.x * 256 + threadIdx.x;  // over TOK*DMODEL/4
    if (i >= TOK * DMODEL / 4) return;
    float s[4] = {0.f, 0.f, 0.f, 0.f};
#pragma unroll
    for (int k = 0; k < KSO; ++k) {
        const ushort4 p = reinterpret_cast<const ushort4*>(
            &part[(size_t)k * (TOK * DMODEL)])[i];
        s[0] += bf2f(p.x); s[1] += bf2f(p.y); s[2] += bf2f(p.z); s[3] += bf2f(p.w);
    }
    if (MODE == 0) {
        ushort4 o;
        o.x = f2bf(s[0]); o.y = f2bf(s[1]); o.z = f2bf(s[2]); o.w = f2bf(s[3]);
        reinterpret_cast<ushort4*>(outp)[i] = o;
    } else {
        const float4 rr = reinterpret_cast<const float4*>(resid)[i];
        float4 o;
        o.x = s[0] + rr.x; o.y = s[1] + rr.y; o.z = s[2] + rr.z; o.w = s[3] + rr.w;
        reinterpret_cast<float4*>(outp)[i] = o;
    }
}

// ---------------------------------------------------------------------------
// Causal depthwise conv1d (+bias) + SiLU; bf16 input, fp32+bf16 output.
// ---------------------------------------------------------------------------
__global__ __launch_bounds__(256)
void conv_silu(const unsigned short* __restrict__ xz_bf,
               const float* __restrict__ cw,
               const float* __restrict__ cb,
               float* __restrict__ u,
               unsigned short* __restrict__ u_bf) {
    const int idx = blockIdx.x * 256 + threadIdx.x;
    const int d = idx & (DINNER - 1);
    const int token = idx >> 11;
    const int l = token & (SEQ - 1);
    float acc = cb[d];
#pragma unroll
    for (int k = 0; k < DCONV; ++k) {
        const int li = l - (DCONV - 1) + k;
        if (li >= 0)
            acc = fmaf(cw[d * DCONV + k],
                       bf2f(xz_bf[(size_t)(token - (DCONV - 1) + k) * (2 * DINNER) + d]),
                       acc);
    }
    const float uv = siluf(acc);
    u[idx] = uv;
    u_bf[idx] = f2bf(uv);
}

// ---------------------------------------------------------------------------
// Chunk-parallel selective scan, register-state (16 states/thread).
// ---------------------------------------------------------------------------
__device__ __forceinline__ void load_b16(const float* __restrict__ p, float* B) {
    const float4* bp = reinterpret_cast<const float4*>(p);
    const float4 b0 = bp[0], b1 = bp[1], b2 = bp[2], b3 = bp[3];
    B[0] = b0.x; B[1] = b0.y; B[2] = b0.z; B[3] = b0.w;
    B[4] = b1.x; B[5] = b1.y; B[6] = b1.z; B[7] = b1.w;
    B[8] = b2.x; B[9] = b2.y; B[10] = b2.z; B[11] = b2.w;
    B[12] = b3.x; B[13] = b3.y; B[14] = b3.z; B[15] = b3.w;
}

__global__ __launch_bounds__(256)
void scan_partial(const float* __restrict__ delta,
                  const float* __restrict__ u,
                  const float* __restrict__ xdbl,
                  const float* __restrict__ A_log,
                  float* __restrict__ hbuf,
                  float* __restrict__ Pbuf) {
    const int b = blockIdx.y / NCHUNK;
    const int c = blockIdx.y % NCHUNK;
    const int d = blockIdx.x * 256 + threadIdx.x;
    const int t0 = b * SEQ + c * CLEN;

    float A_dn[16];
    load_b16(&A_log[d * DSTATE], A_dn);
#pragma unroll
    for (int n = 0; n < 16; ++n) A_dn[n] = -__expf(A_dn[n]);

    float h[16], P[16];
#pragma unroll
    for (int n = 0; n < 16; ++n) { h[n] = 0.f; P[n] = 1.f; }

    float dltA, uvA, BA[16];
    float dltB, uvB, BB[16];
    dltA = delta[(size_t)t0 * DINNER + d];
    uvA = u[(size_t)t0 * DINNER + d];
    load_b16(&xdbl[(size_t)t0 * 96 + DTRANK], BA);

#define PSTEP(dlt_, uv_, Bc_)                              \
    {                                                      \
        const float du = (dlt_) * (uv_);                   \
        _Pragma("unroll")                                  \
        for (int n = 0; n < 16; ++n) {                     \
            const float dA = __expf((dlt_) * A_dn[n]);     \
            h[n] = fmaf(dA, h[n], du * Bc_[n]);            \
            P[n] *= dA;                                    \
        }                                                  \
    }

    for (int l = 0; l < CLEN; l += 2) {
        const int t = t0 + l;
        dltB = delta[(size_t)(t + 1) * DINNER + d];
        uvB = u[(size_t)(t + 1) * DINNER + d];
        load_b16(&xdbl[(size_t)(t + 1) * 96 + DTRANK], BB);
        PSTEP(dltA, uvA, BA);
        if (l + 2 < CLEN) {
            dltA = delta[(size_t)(t + 2) * DINNER + d];
            uvA = u[(size_t)(t + 2) * DINNER + d];
            load_b16(&xdbl[(size_t)(t + 2) * 96 + DTRANK], BA);
        }
        PSTEP(dltB, uvB, BB);
    }
#undef PSTEP

    float* hp = &hbuf[((size_t)(b * NCHUNK + c) * DINNER + d) * DSTATE];
    float* Pp = &Pbuf[((size_t)(b * NCHUNK + c) * DINNER + d) * DSTATE];
#pragma unroll
    for (int q = 0; q < 4; ++q) {
        reinterpret_cast<float4*>(hp)[q] = make_float4(h[q*4], h[q*4+1], h[q*4+2], h[q*4+3]);
        reinterpret_cast<float4*>(Pp)[q] = make_float4(P[q*4], P[q*4+1], P[q*4+2], P[q*4+3]);
    }
}

__global__ __launch_bounds__(256)
void scan_combine(float* __restrict__ hbuf, const float* __restrict__ Pbuf) {
    const int gid = blockIdx.x * 256 + threadIdx.x;  // over BATCH*DINNER*DSTATE
    const int b = gid / (DINNER * DSTATE);
    const int dn = gid - b * (DINNER * DSTATE);
    const size_t base = (size_t)b * NCHUNK * DINNER * DSTATE + dn;
    float hi = 0.f;
#pragma unroll
    for (int c = 0; c < NCHUNK; ++c) {
        const size_t idx = base + (size_t)c * (DINNER * DSTATE);
        const float hl = hbuf[idx];
        const float Pc = Pbuf[idx];
        hbuf[idx] = hi;
        hi = fmaf(Pc, hi, hl);
    }
}

__global__ __launch_bounds__(256)
void scan_final(const float* __restrict__ delta,
                const float* __restrict__ u,
                const float* __restrict__ xdbl,
                const unsigned short* __restrict__ xz_bf,  // z at col 2048+d
                const float* __restrict__ A_log,
                const float* __restrict__ Dp,
                const float* __restrict__ hbuf,
                unsigned short* __restrict__ yout) {
    const int b = blockIdx.y / NCHUNK;
    const int c = blockIdx.y % NCHUNK;
    const int d = blockIdx.x * 256 + threadIdx.x;
    const int t0 = b * SEQ + c * CLEN;

    float A_dn[16];
    load_b16(&A_log[d * DSTATE], A_dn);
#pragma unroll
    for (int n = 0; n < 16; ++n) A_dn[n] = -__expf(A_dn[n]);
    const float Dd = Dp[d];

    float h[16];
    load_b16(&hbuf[((size_t)(b * NCHUNK + c) * DINNER + d) * DSTATE], h);

    float dltA, uvA, BA[16], CA[16];
    float dltB, uvB, BB[16], CB[16];
    dltA = delta[(size_t)t0 * DINNER + d];
    uvA = u[(size_t)t0 * DINNER + d];
    load_b16(&xdbl[(size_t)t0 * 96 + DTRANK], BA);
    load_b16(&xdbl[(size_t)t0 * 96 + DTRANK + DSTATE], CA);

#define FSTEP(t_, dlt_, uv_, Bc_, Cc_)                          \
    {                                                           \
        const float du = (dlt_) * (uv_);                        \
        _Pragma("unroll")                                       \
        for (int n = 0; n < 16; ++n) {                          \
            const float dA = __expf((dlt_) * A_dn[n]);          \
            h[n] = fmaf(dA, h[n], du * Bc_[n]);                 \
        }                                                       \
        float s0 = 0.f, s1 = 0.f, s2 = 0.f, s3 = 0.f;           \
        _Pragma("unroll")                                       \
        for (int q = 0; q < 4; ++q) {                           \
            s0 = fmaf(h[q*4+0], Cc_[q*4+0], s0);                \
            s1 = fmaf(h[q*4+1], Cc_[q*4+1], s1);                \
            s2 = fmaf(h[q*4+2], Cc_[q*4+2], s2);                \
            s3 = fmaf(h[q*4+3], Cc_[q*4+3], s3);                \
        }                                                       \
        const float zv = bf2f(xz_bf[(size_t)(t_) * (2 * DINNER) + DINNER + d]); \
        const float y = (s0 + s1) + (s2 + s3) + (uv_) * Dd;     \
        yout[(size_t)(t_) * DINNER + d] = f2bf(y * siluf(zv));  \
    }

    for (int l = 0; l < CLEN; l += 2) {
        const int t = t0 + l;
        dltB = delta[(size_t)(t + 1) * DINNER + d];
        uvB = u[(size_t)(t + 1) * DINNER + d];
        load_b16(&xdbl[(size_t)(t + 1) * 96 + DTRANK], BB);
        load_b16(&xdbl[(size_t)(t + 1) * 96 + DTRANK + DSTATE], CB);
        FSTEP(t, dltA, uvA, BA, CA);
        if (l + 2 < CLEN) {
            dltA = delta[(size_t)(t + 2) * DINNER + d];
            uvA = u[(size_t)(t + 2) * DINNER + d];
            load_b16(&xdbl[(size_t)(t + 2) * 96 + DTRANK], BA);
            load_b16(&xdbl[(size_t)(t + 2) * 96 + DTRANK + DSTATE], CA);
        }
        FSTEP(t + 1, dltB, uvB, BB, CB);
    }
#undef FSTEP
}

// ---------------------------------------------------------------------------
extern "C" void kernel_launch(void* const* d_in, const int* in_sizes, int n_in,
                              void* d_out, int out_size, void* d_ws, size_t ws_size,
                              hipStream_t stream) {
    const float* x          = (const float*)d_in[0];
    const float* in_proj_w  = (const float*)d_in[1];
    const float* conv_w     = (const float*)d_in[2];
    const float* conv_b     = (const float*)d_in[3];
    const float* x_proj_w   = (const float*)d_in[4];
    const float* dt_proj_w  = (const float*)d_in[5];
    const float* dt_proj_b  = (const float*)d_in[6];
    const float* A_log      = (const float*)d_in[7];
    const float* Dp         = (const float*)d_in[8];
    const float* out_proj_w = (const float*)d_in[9];
    float* out = (float*)d_out;

    // workspace layout
    float* ws = (float*)d_ws;
    float* hbuf  = ws;                       // 2*32*2048*16 = 2,097,152
    float* Pbuf  = hbuf  + 2097152;          // 2,097,152
    float* xpart = Pbuf  + 2097152;          // KSX*TOK*96 = 1,572,864
    float* u     = xpart + 1572864;          // 4,194,304
    float* delta = u     + 4194304;          // 4,194,304
    float* xdbl  = delta + 4194304;          // TOK*96 = 196,608
    unsigned short* opart  = (unsigned short*)(xdbl + 196608);  // KSO*TOK*1024 = 8,388,608
    unsigned short* wi_bf  = opart + 8388608;   // 2 layers: 8,388,608
    unsigned short* wo_bf  = wi_bf + 8388608;   // 4,194,304
    unsigned short* wx_bf  = wo_bf + 4194304;   // 393,216
    unsigned short* wd_bf  = wx_bf + 393216;    // 262,144
    unsigned short* xz_bf  = wd_bf + 262144;    // TOK*4096 = 8,388,608
    unsigned short* u_bf   = xz_bf + 8388608;   // 4,194,304
    unsigned short* act_bf = u_bf  + 4194304;   // 2,097,152
    unsigned short* y_bf   = act_bf + 2097152;  // 4,194,304
    unsigned short* dt_bf  = y_bf  + 4194304;   // TOK*64 = 131,072

    // one-time conversions
    cvt_weights<<<(WI8 + WO8 + WX8 + WD8 + 255) / 256, 256, 0, stream>>>(
        in_proj_w, out_proj_w, x_proj_w, dt_proj_w, wi_bf, wo_bf, wx_bf, wd_bf);
    cvt_f32_bf16<<<(TOK * DMODEL / 8 + 255) / 256, 256, 0, stream>>>(
        x, act_bf, TOK * DMODEL / 8);

    for (int layer = 0; layer < NLAYERS; ++layer) {
        const unsigned short* Wi = wi_bf + (size_t)layer * (2 * DINNER) * DMODEL;
        const unsigned short* Wo = wo_bf + (size_t)layer * DMODEL * DINNER;
        const unsigned short* Wx = wx_bf + (size_t)layer * 96 * DINNER;
        const unsigned short* Wd = wd_bf + (size_t)layer * DINNER * DTRANK;
        const float* cw = conv_w    + (size_t)layer * DINNER * DCONV;
        const float* cb = conv_b    + (size_t)layer * DINNER;
        const float* bd = dt_proj_b + (size_t)layer * DINNER;
        const float* Al = A_log     + (size_t)layer * DINNER * DSTATE;
        const float* Dl = Dp        + (size_t)layer * DINNER;

        // 1. xz = act @ W_in^T -> bf16  (TOK x 4096, K=1024)
        {
            dim3 grid(4096 / 128, TOK / 128, 1);
            gemm_bf16<3><<<grid, 256, 0, stream>>>(act_bf, DMODEL, Wi, DMODEL,
                                                   xz_bf, 2 * DINNER, DMODEL,
                                                   2 * DINNER, 0, nullptr);
        }
        // 2. u = silu(conv(xc)+b) -> fp32 + bf16
        conv_silu<<<(TOK * DINNER) / 256, 256, 0, stream>>>(xz_bf, cw, cb, u, u_bf);
        // 3. x_dbl partials = u_bf @ Wx^T (TOK x 96, K=2048, split-K8)
        {
            dim3 grid(1, TOK / 128, KSX);
            gemm_bf16<0><<<grid, 256, 0, stream>>>(u_bf, DINNER, Wx, DINNER,
                                                   xpart, 96, DINNER / KSX, 96,
                                                   (size_t)TOK * 96, nullptr);
            reduce_x<<<(TOK * 96 + 255) / 256, 256, 0, stream>>>(xpart, xdbl, dt_bf);
        }
        // 4. delta = softplus(dt_bf @ Wd^T + b)  (TOK x 2048, K=64)
        {
            dim3 grid(DINNER / 128, TOK / 128, 1);
            gemm_bf16<1><<<grid, 256, 0, stream>>>(dt_bf, DTRANK, Wd, DTRANK,
                                                   delta, DINNER, DTRANK, DINNER,
                                                   0, bd);
        }
        // 5. chunk-parallel scan -> y_bf
        {
            dim3 gridA(DINNER / 256, BATCH * NCHUNK);
            scan_partial<<<gridA, 256, 0, stream>>>(delta, u, xdbl, Al, hbuf, Pbuf);
            scan_combine<<<(BATCH * DINNER * DSTATE) / 256, 256, 0, stream>>>(hbuf, Pbuf);
            scan_final<<<gridA, 256, 0, stream>>>(delta, u, xdbl, xz_bf, Al, Dl,
                                                  hbuf, y_bf);
        }
        // 6. out partials = y_bf @ Wo^T (TOK x 1024, K=2048, split-K4) -> reduce
        {
            dim3 grid(DMODEL / 128, TOK / 128, KSO);
            gemm_bf16<3><<<grid, 256, 0, stream>>>(y_bf, DINNER, Wo, DINNER,
                                                   opart, DMODEL, DINNER / KSO,
                                                   DMODEL, (size_t)TOK * DMODEL,
                                                   nullptr);
            const int nred = TOK * DMODEL / 4;
            if (layer == NLAYERS - 1) {
                reduce_out<1><<<(nred + 255) / 256, 256, 0, stream>>>(opart, x, out);
            } else {
                reduce_out<0><<<(nred + 255) / 256, 256, 0, stream>>>(opart, nullptr,
                                                                      act_bf);
            }
        }
    }
}